// Round 1
// baseline (1563.001 us; speedup 1.0000x reference)
//
#include <hip/hip_runtime.h>
#include <hip/hip_bf16.h>
#include <math.h>

// Problem dims (fixed)
#define TT   64
#define BBATCH 64
#define NTOK 64
#define DDIM 128
#define HIDN 256
#define BN   4096     // BBATCH*NTOK

typedef short bf16x8 __attribute__((ext_vector_type(8)));
typedef float f32x4  __attribute__((ext_vector_type(4)));

// ---------------------------------------------------------------------------
// G = C_low^T C_low : symmetric 64x64 Gram of the first 16 orthonormal DCT-II
// rows. lowpass_time(x) == G @ x along time (k=0 row makes the mean re-add
// exact in exact arithmetic; fp32 noise is the same class as matmul reorder).
// ---------------------------------------------------------------------------
__global__ void k_gram(float* __restrict__ G) {
  int s = blockIdx.x, t = threadIdx.x;
  double acc = 0.0;
  for (int k = 0; k < 16; ++k) {
    double ct, cs;
    if (k == 0) { ct = 0.125; cs = 0.125; }  // sqrt(1/64)
    else {
      const double f = 0.17677669529663687;  // sqrt(2/64)
      ct = cos(M_PI * (t + 0.5) * k / 64.0) * f;
      cs = cos(M_PI * (s + 0.5) * k / 64.0) * f;
    }
    acc += ct * cs;
  }
  G[s * 64 + t] = (float)acc;
}

// ---------------------------------------------------------------------------
// xlp[t,b,n,:] = sum_s G[t,s] * ( x[s,b,n,:] * (0.05*mx[n,b,s,:]+0.95*mx[n,b,s,:]) )
// One block per (b,n). m2 tile staged in LDS; G read via wave-uniform scalar
// loads (s is per-wave uniform); two s-halves reduced through LDS.
// ---------------------------------------------------------------------------
__global__ __launch_bounds__(256) void k_lowpass(
    const float* __restrict__ x, const float* __restrict__ mx,
    const float* __restrict__ G, float* __restrict__ xlp) {
  __shared__ float m2[64 * 132];  // [s][d], stride 132 (bank-safe, 16B aligned)
  const int bn = blockIdx.x;
  const int b = bn >> 6, n = bn & 63;
  const float* mxs = mx + (size_t)(n * 64 + b) * 8192;  // (n,b) slab, contiguous
#pragma unroll
  for (int i = 0; i < 8; ++i) {
    int idx4 = threadIdx.x + i * 256;          // 0..2047 float4s
    int s = idx4 >> 5, dq = (idx4 & 31) * 4;
    const float4 xv = *(const float4*)&x[(size_t)(s * 4096 + bn) * 128 + dq];
    const float4 mv = *(const float4*)&mxs[idx4 * 4];
    float4 r;
    {
#pragma clang fp contract(off)
      // replicate reference rounding: fl(fl(.05m)+fl(.95m)) then * x
      r.x = xv.x * (0.05f * mv.x + 0.95f * mv.x);
      r.y = xv.y * (0.05f * mv.y + 0.95f * mv.y);
      r.z = xv.z * (0.05f * mv.z + 0.95f * mv.z);
      r.w = xv.w * (0.05f * mv.w + 0.95f * mv.w);
    }
    *(float4*)&m2[s * 132 + dq] = r;
  }
  __syncthreads();
  const int d = threadIdx.x & 127, shh = threadIdx.x >> 7;  // s-half per wave-pair
  float acc[64];
#pragma unroll
  for (int t = 0; t < 64; ++t) acc[t] = 0.f;
  for (int si = 0; si < 32; ++si) {
    int s = shh * 32 + si;
    float mval = m2[s * 132 + d];
    const float* Gs = G + s * 64;  // wave-uniform -> s_load; G symmetric
#pragma unroll
    for (int t = 0; t < 64; ++t) acc[t] = fmaf(Gs[t], mval, acc[t]);
  }
  __syncthreads();
  float* part = m2;  // reuse LDS: [d][t] stride 66
  if (shh == 1) {
#pragma unroll
    for (int t = 0; t < 64; ++t) part[d * 66 + t] = acc[t];
  }
  __syncthreads();
  if (shh == 0) {
#pragma unroll
    for (int t = 0; t < 64; ++t) {
      float v = acc[t] + part[d * 66 + t];
      xlp[(size_t)(t * 4096 + bn) * 128 + d] = v;
    }
  }
}

// ---------------------------------------------------------------------------
// Fused GEMM + LIF (+ optional multiplicative gate) per (b,n):
//   pre[t][c] = sum_k A[(t,b,n)][k] * W[k][c0+c],  t=0..63, c=0..127
//   LIF scan over t per column; output either bf16 spike bits (0x3F80/0) or
//   gated fp32:  out = gate * (1 - spike)  (exact select since spike in {0,1}).
// A rows live at (t*4096+bn)*KDIM.
// A tile: [t][k] layout, row stride 64 floats (256B), per-row XOR quad-swizzle
//   pos(t,q) = t*64 + 4*(q ^ ((t>>2)&7))   (q = k/4, bijective per row).
//   -> staged with float4 global loads + b128 LDS writes; compute reads one
//   ds_read_b128 per row per k-quad, 16 distinct addrs spread over all 32
//   banks (2 addr/bank = free baseline). Cuts LDS insts per k-quad 24 -> 12.
// B tile: [k][c] stride 128 (reads are 4-distinct-addr b128 broadcasts).
// C reuses A/B LDS after barrier (stride 132).
// ---------------------------------------------------------------------------
template <int KDIM, bool ABF16, bool GATE>
__global__ __launch_bounds__(256) void k_gemm_lif(
    const void* __restrict__ Ap, const float* __restrict__ W, const int NW,
    const float* __restrict__ gate, void* __restrict__ outp) {
  __shared__ float smem[64 * 64 + 64 * 128];  // 49152 B -> 3 blocks/CU
  float* Al = smem;            // [t][k] swizzled, stride 64
  float* Bl = smem + 64 * 64;
  const int bn = blockIdx.x;
  const int c0 = blockIdx.y * 128;
  const int mq = threadIdx.x & 15;   // t-quad: rows mq*4..mq*4+3
  const int ng = threadIdx.x >> 4;   // col-octet: cols ng*8..ng*8+7
  float acc[4][8];
#pragma unroll
  for (int i = 0; i < 4; ++i)
#pragma unroll
    for (int j = 0; j < 8; ++j) acc[i][j] = 0.f;

  for (int kc = 0; kc < KDIM; kc += 64) {
    if (!ABF16) {  // stage A chunk: float4 global loads, swizzled b128 writes
      const int q = threadIdx.x & 15, tq = threadIdx.x >> 4;
#pragma unroll
      for (int p = 0; p < 4; ++p) {
        int t = p * 16 + tq;
        const float4 v = *(const float4*)&(
            (const float*)Ap)[(size_t)(t * 4096 + bn) * KDIM + kc + q * 4];
        *(float4*)&Al[t * 64 + 4 * (q ^ ((t >> 2) & 7))] = v;
      }
    } else {  // bf16 A: uint4 = 8 halfs -> 2 swizzled quads
      const int ko = threadIdx.x & 7, tq = threadIdx.x >> 3;
#pragma unroll
      for (int p = 0; p < 2; ++p) {
        int t = p * 32 + tq;
        const uint4 v = *(const uint4*)&((const unsigned short*)
            Ap)[(size_t)(t * 4096 + bn) * KDIM + kc + ko * 8];
        unsigned u[4] = {v.x, v.y, v.z, v.w};
        float f[8];
#pragma unroll
        for (int e = 0; e < 4; ++e) {
          f[2 * e]     = __uint_as_float((u[e] & 0xFFFFu) << 16);
          f[2 * e + 1] = __uint_as_float(u[e] & 0xFFFF0000u);
        }
        int sw = (t >> 2) & 7;
        *(float4*)&Al[t * 64 + 4 * ((2 * ko) ^ sw)] =
            make_float4(f[0], f[1], f[2], f[3]);
        *(float4*)&Al[t * 64 + 4 * ((2 * ko + 1) ^ sw)] =
            make_float4(f[4], f[5], f[6], f[7]);
      }
    }
#pragma unroll
    for (int j = 0; j < 8; ++j) {  // stage B chunk (64x128 f32), float4 coalesced
      int idx = threadIdx.x + j * 256;
      int k = idx >> 5, cq = (idx & 31) * 4;
      *(float4*)&Bl[k * 128 + cq] = *(const float4*)&W[(size_t)(kc + k) * NW + c0 + cq];
    }
    __syncthreads();
    const int sw = mq & 7;  // == (row>>2)&7 for rows mq*4..mq*4+3
#pragma unroll 2
    for (int kq = 0; kq < 16; ++kq) {
      float4 av[4];
#pragma unroll
      for (int i = 0; i < 4; ++i)
        av[i] = *(const float4*)&Al[(mq * 4 + i) * 64 + 4 * (kq ^ sw)];
#pragma unroll
      for (int kk = 0; kk < 4; ++kk) {
        float bv[8];
        *(float4*)&bv[0] = *(const float4*)&Bl[(kq * 4 + kk) * 128 + ng * 8];
        *(float4*)&bv[4] = *(const float4*)&Bl[(kq * 4 + kk) * 128 + ng * 8 + 4];
        float a0 = av[0][kk], a1 = av[1][kk], a2 = av[2][kk], a3 = av[3][kk];
#pragma unroll
        for (int j = 0; j < 8; ++j) {
          acc[0][j] = fmaf(a0, bv[j], acc[0][j]);
          acc[1][j] = fmaf(a1, bv[j], acc[1][j]);
          acc[2][j] = fmaf(a2, bv[j], acc[2][j]);
          acc[3][j] = fmaf(a3, bv[j], acc[3][j]);
        }
      }
    }
    __syncthreads();
  }
  // scatter C tile to LDS [t][c] (stride 132), then LIF scan per column
  float* Cl = smem;
#pragma unroll
  for (int i = 0; i < 4; ++i) {
    *(float4*)&Cl[(mq * 4 + i) * 132 + ng * 8] =
        make_float4(acc[i][0], acc[i][1], acc[i][2], acc[i][3]);
    *(float4*)&Cl[(mq * 4 + i) * 132 + ng * 8 + 4] =
        make_float4(acc[i][4], acc[i][5], acc[i][6], acc[i][7]);
  }
  __syncthreads();
  if (threadIdx.x < 128) {
    const int c = threadIdx.x;
    float v = 0.f;
    for (int t = 0; t < 64; ++t) {
      float pre = Cl[t * 132 + c];
      {
#pragma clang fp contract(off)
        float dlt = (pre - v) * 0.5f;  // v + (c-v)/tau, tau=2 (exact /2)
        v = v + dlt;
      }
      bool s = (v >= 1.0f);
      size_t orow = (size_t)(t * 4096 + bn);
      if (GATE) {
        float g = gate[orow * 128 + c];
        ((float*)outp)[orow * 128 + c] = s ? 0.f : g;  // g*(1-s) exact
      } else {
        ((unsigned short*)outp)[orow * NW + c0 + c] =
            s ? (unsigned short)0x3F80 : (unsigned short)0;  // bf16 1.0 / 0.0
      }
      v = s ? 0.f : v;  // hard reset
    }
  }
}

// ---------------------------------------------------------------------------
// Spiking 2-head attention per (t,b):  S = q k^T * 0.125 ; O = S v. No softmax.
// Exact in bf16 MFMA: spikes in {0,1}; S integer<=64 (bf16-exact after *1/8);
// O = multiples of 1/8 <= 512 (fp32-exact). Wave w owns n-rows [w*16,w*16+16).
// ---------------------------------------------------------------------------
__global__ __launch_bounds__(256) void k_attn(
    const unsigned short* __restrict__ q, const unsigned short* __restrict__ kk,
    const unsigned short* __restrict__ vv, float* __restrict__ o) {
  __shared__ unsigned short ql[64 * 136];  // [n][d] bf16 bits
  __shared__ unsigned short kl[64 * 136];
  __shared__ unsigned short vt[128 * 72];  // [d][m] (v transposed)
  __shared__ unsigned short sl[64 * 72];   // S' [n][m] per head (reused)
  const size_t base = (size_t)blockIdx.x * 8192;
#pragma unroll
  for (int i = 0; i < 4; ++i) {
    int idx8 = threadIdx.x + i * 256;     // 1024 x 8-elem chunks
    int n = idx8 >> 4, d8 = (idx8 & 15) * 8;
    uint4 pq = *(const uint4*)&q[base + n * 128 + d8];
    uint4 pk = *(const uint4*)&kk[base + n * 128 + d8];
    *(uint4*)&ql[n * 136 + d8] = pq;
    *(uint4*)&kl[n * 136 + d8] = pk;
    uint4 pv = *(const uint4*)&vv[base + n * 128 + d8];
    unsigned short e[8] = {
        (unsigned short)(pv.x & 0xFFFF), (unsigned short)(pv.x >> 16),
        (unsigned short)(pv.y & 0xFFFF), (unsigned short)(pv.y >> 16),
        (unsigned short)(pv.z & 0xFFFF), (unsigned short)(pv.z >> 16),
        (unsigned short)(pv.w & 0xFFFF), (unsigned short)(pv.w >> 16)};
#pragma unroll
    for (int j = 0; j < 8; ++j) vt[(d8 + j) * 72 + n] = e[j];
  }
  __syncthreads();
  const int lane = threadIdx.x & 63;
  const int w = threadIdx.x >> 6;          // wave id = n-tile (ti)
  const int l15 = lane & 15, l4 = lane >> 4;
  for (int h = 0; h < 2; ++h) {
    // phase 1: S tiles (ti=w, tj=0..3), K = dh = 64 (2 MFMA k-steps)
    bf16x8 af0 = *(const bf16x8*)&ql[(w * 16 + l15) * 136 + h * 64 + l4 * 8];
    bf16x8 af1 = *(const bf16x8*)&ql[(w * 16 + l15) * 136 + h * 64 + 32 + l4 * 8];
#pragma unroll
    for (int tj = 0; tj < 4; ++tj) {
      f32x4 c = {0.f, 0.f, 0.f, 0.f};
      bf16x8 b0 = *(const bf16x8*)&kl[(tj * 16 + l15) * 136 + h * 64 + l4 * 8];
      c = __builtin_amdgcn_mfma_f32_16x16x32_bf16(af0, b0, c, 0, 0, 0);
      bf16x8 b1 = *(const bf16x8*)&kl[(tj * 16 + l15) * 136 + h * 64 + 32 + l4 * 8];
      c = __builtin_amdgcn_mfma_f32_16x16x32_bf16(af1, b1, c, 0, 0, 0);
#pragma unroll
      for (int r = 0; r < 4; ++r) {
        float sp = c[r] * 0.125f;  // exact; low 16 mantissa bits are zero
        sl[(w * 16 + l4 * 4 + r) * 72 + tj * 16 + l15] =
            (unsigned short)(__float_as_uint(sp) >> 16);
      }
    }
    __syncthreads();
    // phase 2: O tiles (ti=w, tj over dh), K = m = 64
    bf16x8 a20 = *(const bf16x8*)&sl[(w * 16 + l15) * 72 + l4 * 8];
    bf16x8 a21 = *(const bf16x8*)&sl[(w * 16 + l15) * 72 + 32 + l4 * 8];
#pragma unroll
    for (int tj = 0; tj < 4; ++tj) {
      f32x4 c = {0.f, 0.f, 0.f, 0.f};
      bf16x8 b0 = *(const bf16x8*)&vt[(h * 64 + tj * 16 + l15) * 72 + l4 * 8];
      c = __builtin_amdgcn_mfma_f32_16x16x32_bf16(a20, b0, c, 0, 0, 0);
      bf16x8 b1 = *(const bf16x8*)&vt[(h * 64 + tj * 16 + l15) * 72 + 32 + l4 * 8];
      c = __builtin_amdgcn_mfma_f32_16x16x32_bf16(a21, b1, c, 0, 0, 0);
#pragma unroll
      for (int r = 0; r < 4; ++r)
        o[base + (size_t)(w * 16 + l4 * 4 + r) * 128 + h * 64 + tj * 16 + l15] = c[r];
    }
    __syncthreads();  // sl reused by next head
  }
}

// ---------------------------------------------------------------------------
extern "C" void kernel_launch(void* const* d_in, const int* in_sizes, int n_in,
                              void* d_out, int out_size, void* d_ws, size_t ws_size,
                              hipStream_t stream) {
  const float* x  = (const float*)d_in[0];
  const float* mx = (const float*)d_in[1];
  const float* Wq = (const float*)d_in[2];
  const float* Wk = (const float*)d_in[3];
  const float* Wv = (const float*)d_in[4];
  const float* Wo = (const float*)d_in[5];
  const float* W1 = (const float*)d_in[6];
  const float* W2 = (const float*)d_in[7];
  float* out = (float*)d_out;

  // workspace layout (~470 MB):
  char* w = (char*)d_ws;
  float* G   = (float*)w;                                   // 16 KB (pad 64K)
  float* xlp = (float*)(w + 65536);                         // 134 MB, later o
  float* x2  = (float*)(w + 65536 + 134217728ull);          // 134 MB
  unsigned short* sq = (unsigned short*)(w + 65536 + 268435456ull);  // 67 MB
  unsigned short* sk = sq + 33554432ull;                    // 67 MB
  unsigned short* sv = sk + 33554432ull;                    // 67 MB
  unsigned short* sh = sq;  // mlp hidden spikes overlay sq+sk (134 MB)

  k_gram<<<64, 64, 0, stream>>>(G);
  k_lowpass<<<4096, 256, 0, stream>>>(x, mx, G, xlp);
  // q from x; k,v from lowpassed memory stream
  k_gemm_lif<128, false, false><<<dim3(4096, 1), 256, 0, stream>>>(x,   Wq, 128, nullptr, sq);
  k_gemm_lif<128, false, false><<<dim3(4096, 1), 256, 0, stream>>>(xlp, Wk, 128, nullptr, sk);
  k_gemm_lif<128, false, false><<<dim3(4096, 1), 256, 0, stream>>>(xlp, Wv, 128, nullptr, sv);
  k_attn<<<4096, 256, 0, stream>>>(sq, sk, sv, xlp);  // o overwrites xlp
  // attn_spk = lif(o @ Wo); x2 = x * (1 - attn_spk)
  k_gemm_lif<128, false, true ><<<dim3(4096, 1), 256, 0, stream>>>(xlp, Wo, 128, x, x2);
  // mlp: h = lif(x2 @ W1) (HID=256 -> grid.y=2); out = x2 * (1 - lif(h @ W2))
  k_gemm_lif<128, false, false><<<dim3(4096, 2), 256, 0, stream>>>(x2, W1, 256, nullptr, sh);
  k_gemm_lif<256, true,  true ><<<dim3(4096, 1), 256, 0, stream>>>(sh, W2, 128, x2, out);
}

// Round 2
// 1513.472 us; speedup vs baseline: 1.0327x; 1.0327x over previous
//
#include <hip/hip_runtime.h>
#include <hip/hip_bf16.h>
#include <math.h>

// Problem dims (fixed)
#define TT   64
#define BBATCH 64
#define NTOK 64
#define DDIM 128
#define HIDN 256
#define BN   4096     // BBATCH*NTOK

typedef short bf16x8 __attribute__((ext_vector_type(8)));
typedef float f32x4  __attribute__((ext_vector_type(4)));

// ---------------------------------------------------------------------------
// G = C_low^T C_low : symmetric 64x64 Gram of the first 16 orthonormal DCT-II
// rows. lowpass_time(x) == G @ x along time.
// ---------------------------------------------------------------------------
__global__ void k_gram(float* __restrict__ G) {
  int s = blockIdx.x, t = threadIdx.x;
  double acc = 0.0;
  for (int k = 0; k < 16; ++k) {
    double ct, cs;
    if (k == 0) { ct = 0.125; cs = 0.125; }  // sqrt(1/64)
    else {
      const double f = 0.17677669529663687;  // sqrt(2/64)
      ct = cos(M_PI * (t + 0.5) * k / 64.0) * f;
      cs = cos(M_PI * (s + 0.5) * k / 64.0) * f;
    }
    acc += ct * cs;
  }
  G[s * 64 + t] = (float)acc;
}

// ---------------------------------------------------------------------------
// 3-way exact bf16 split of W2, stored transposed [c][k] per plane:
//   W = hi + mid + lo  (8+8+8 mantissa bits; residual below fp32 noise).
// Planes: Wt[0..32767]=hi, +32768=mid, +65536=lo.
// ---------------------------------------------------------------------------
__global__ void k_prep_w2(const float* __restrict__ W2, unsigned short* __restrict__ Wt) {
  int idx = blockIdx.x * 256 + threadIdx.x;  // k*128 + c, 32768 total
  int k = idx >> 7, c = idx & 127;
  float w = W2[idx];
  unsigned uh = (__float_as_uint(w) + 0x7FFF + ((__float_as_uint(w) >> 16) & 1)) & 0xFFFF0000u;
  float fh = __uint_as_float(uh);
  float r1 = w - fh;
  unsigned um = (__float_as_uint(r1) + 0x7FFF + ((__float_as_uint(r1) >> 16) & 1)) & 0xFFFF0000u;
  float fm = __uint_as_float(um);
  float r2 = r1 - fm;
  unsigned ul = (__float_as_uint(r2) + 0x7FFF + ((__float_as_uint(r2) >> 16) & 1)) & 0xFFFF0000u;
  Wt[c * 256 + k]         = (unsigned short)(uh >> 16);
  Wt[32768 + c * 256 + k] = (unsigned short)(um >> 16);
  Wt[65536 + c * 256 + k] = (unsigned short)(ul >> 16);
}

// ---------------------------------------------------------------------------
// k_lowpass v2: xlp tile (64t x 128d) = G(64x64) @ m2(64s x 128d) per (b,n)
// block, using the proven k_gemm_lif inner loop. A = G (XOR-quad-swizzled,
// stride 64), B = m2 product staged [s][d] stride 128. No SMEM loads in the
// hot loop (the v1 kernel mixed s_load(G) with ds_read -> lgkmcnt(0)
// serialization, 11% VALUBusy). Direct f32 epilogue (no LIF).
// ---------------------------------------------------------------------------
__global__ __launch_bounds__(256) void k_lowpass(
    const float* __restrict__ x, const float* __restrict__ mx,
    const float* __restrict__ G, float* __restrict__ xlp) {
  __shared__ float smem[64 * 64 + 64 * 128];  // 49152 B -> 3 blocks/CU
  float* Al = smem;            // G [t][s] swizzled, stride 64
  float* Bl = smem + 64 * 64;  // m2 [s][d], stride 128
  const int bn = blockIdx.x;
  const int b = bn >> 6, n = bn & 63;
  const float* mxs = mx + (size_t)(n * 64 + b) * 8192;  // (n,b) slab, contiguous
  {  // stage G: 4 float4/thread, store-side swizzle (matches k_gemm_lif A)
    const int q = threadIdx.x & 15, tq = threadIdx.x >> 4;
#pragma unroll
    for (int p = 0; p < 4; ++p) {
      int t = p * 16 + tq;
      const float4 v = *(const float4*)&G[t * 64 + q * 4];
      *(float4*)&Al[t * 64 + 4 * (q ^ ((t >> 2) & 7))] = v;
    }
  }
#pragma unroll
  for (int i = 0; i < 8; ++i) {  // stage m2 = x * (.05mx+.95mx)
    int idx4 = threadIdx.x + i * 256;          // 0..2047 float4s
    int s = idx4 >> 5, dq = (idx4 & 31) * 4;
    const float4 xv = *(const float4*)&x[(size_t)(s * 4096 + bn) * 128 + dq];
    const float4 mv = *(const float4*)&mxs[idx4 * 4];
    float4 r;
    {
#pragma clang fp contract(off)
      // replicate reference rounding: fl(fl(.05m)+fl(.95m)) then * x
      r.x = xv.x * (0.05f * mv.x + 0.95f * mv.x);
      r.y = xv.y * (0.05f * mv.y + 0.95f * mv.y);
      r.z = xv.z * (0.05f * mv.z + 0.95f * mv.z);
      r.w = xv.w * (0.05f * mv.w + 0.95f * mv.w);
    }
    *(float4*)&Bl[s * 128 + dq] = r;
  }
  __syncthreads();
  const int mq = threadIdx.x & 15;   // t-quad: rows mq*4..mq*4+3
  const int ng = threadIdx.x >> 4;   // col-octet: cols ng*8..ng*8+7
  float acc[4][8];
#pragma unroll
  for (int i = 0; i < 4; ++i)
#pragma unroll
    for (int j = 0; j < 8; ++j) acc[i][j] = 0.f;
  const int sw = mq & 7;  // == (row>>2)&7 for rows mq*4..mq*4+3
#pragma unroll 2
  for (int kq = 0; kq < 16; ++kq) {
    float4 av[4];
#pragma unroll
    for (int i = 0; i < 4; ++i)
      av[i] = *(const float4*)&Al[(mq * 4 + i) * 64 + 4 * (kq ^ sw)];
#pragma unroll
    for (int kk = 0; kk < 4; ++kk) {
      float bv[8];
      *(float4*)&bv[0] = *(const float4*)&Bl[(kq * 4 + kk) * 128 + ng * 8];
      *(float4*)&bv[4] = *(const float4*)&Bl[(kq * 4 + kk) * 128 + ng * 8 + 4];
      float a0 = av[0][kk], a1 = av[1][kk], a2 = av[2][kk], a3 = av[3][kk];
#pragma unroll
      for (int j = 0; j < 8; ++j) {
        acc[0][j] = fmaf(a0, bv[j], acc[0][j]);
        acc[1][j] = fmaf(a1, bv[j], acc[1][j]);
        acc[2][j] = fmaf(a2, bv[j], acc[2][j]);
        acc[3][j] = fmaf(a3, bv[j], acc[3][j]);
      }
    }
  }
#pragma unroll
  for (int i = 0; i < 4; ++i) {  // direct store, coalesced per (t,bn) row
    int t = mq * 4 + i;
    size_t row = (size_t)(t * 4096 + bn) * 128;
    *(float4*)&xlp[row + ng * 8] =
        make_float4(acc[i][0], acc[i][1], acc[i][2], acc[i][3]);
    *(float4*)&xlp[row + ng * 8 + 4] =
        make_float4(acc[i][4], acc[i][5], acc[i][6], acc[i][7]);
  }
}

// ---------------------------------------------------------------------------
// Fused GEMM + LIF (+ optional multiplicative gate) per (b,n):
//   pre[t][c] = sum_k A[(t,b,n)][k] * W[k][c0+c],  t=0..63, c=0..127
// A tile: [t][k] layout, stride 64, per-row XOR quad-swizzle (see lowpass).
// B tile: [k][c] stride 128. C reuses A/B LDS after barrier (stride 132).
// ---------------------------------------------------------------------------
template <int KDIM, bool ABF16, bool GATE>
__global__ __launch_bounds__(256) void k_gemm_lif(
    const void* __restrict__ Ap, const float* __restrict__ W, const int NW,
    const float* __restrict__ gate, void* __restrict__ outp) {
  __shared__ float smem[64 * 64 + 64 * 128];  // 49152 B -> 3 blocks/CU
  float* Al = smem;            // [t][k] swizzled, stride 64
  float* Bl = smem + 64 * 64;
  const int bn = blockIdx.x;
  const int c0 = blockIdx.y * 128;
  const int mq = threadIdx.x & 15;   // t-quad: rows mq*4..mq*4+3
  const int ng = threadIdx.x >> 4;   // col-octet: cols ng*8..ng*8+7
  float acc[4][8];
#pragma unroll
  for (int i = 0; i < 4; ++i)
#pragma unroll
    for (int j = 0; j < 8; ++j) acc[i][j] = 0.f;

  for (int kc = 0; kc < KDIM; kc += 64) {
    if (!ABF16) {  // stage A chunk: float4 global loads, swizzled b128 writes
      const int q = threadIdx.x & 15, tq = threadIdx.x >> 4;
#pragma unroll
      for (int p = 0; p < 4; ++p) {
        int t = p * 16 + tq;
        const float4 v = *(const float4*)&(
            (const float*)Ap)[(size_t)(t * 4096 + bn) * KDIM + kc + q * 4];
        *(float4*)&Al[t * 64 + 4 * (q ^ ((t >> 2) & 7))] = v;
      }
    } else {  // bf16 A: uint4 = 8 halfs -> 2 swizzled quads
      const int ko = threadIdx.x & 7, tq = threadIdx.x >> 3;
#pragma unroll
      for (int p = 0; p < 2; ++p) {
        int t = p * 32 + tq;
        const uint4 v = *(const uint4*)&((const unsigned short*)
            Ap)[(size_t)(t * 4096 + bn) * KDIM + kc + ko * 8];
        unsigned u[4] = {v.x, v.y, v.z, v.w};
        float f[8];
#pragma unroll
        for (int e = 0; e < 4; ++e) {
          f[2 * e]     = __uint_as_float((u[e] & 0xFFFFu) << 16);
          f[2 * e + 1] = __uint_as_float(u[e] & 0xFFFF0000u);
        }
        int sw = (t >> 2) & 7;
        *(float4*)&Al[t * 64 + 4 * ((2 * ko) ^ sw)] =
            make_float4(f[0], f[1], f[2], f[3]);
        *(float4*)&Al[t * 64 + 4 * ((2 * ko + 1) ^ sw)] =
            make_float4(f[4], f[5], f[6], f[7]);
      }
    }
#pragma unroll
    for (int j = 0; j < 8; ++j) {  // stage B chunk (64x128 f32), float4 coalesced
      int idx = threadIdx.x + j * 256;
      int k = idx >> 5, cq = (idx & 31) * 4;
      *(float4*)&Bl[k * 128 + cq] = *(const float4*)&W[(size_t)(kc + k) * NW + c0 + cq];
    }
    __syncthreads();
    const int sw = mq & 7;  // == (row>>2)&7 for rows mq*4..mq*4+3
#pragma unroll 2
    for (int kq = 0; kq < 16; ++kq) {
      float4 av[4];
#pragma unroll
      for (int i = 0; i < 4; ++i)
        av[i] = *(const float4*)&Al[(mq * 4 + i) * 64 + 4 * (kq ^ sw)];
#pragma unroll
      for (int kk = 0; kk < 4; ++kk) {
        float bv[8];
        *(float4*)&bv[0] = *(const float4*)&Bl[(kq * 4 + kk) * 128 + ng * 8];
        *(float4*)&bv[4] = *(const float4*)&Bl[(kq * 4 + kk) * 128 + ng * 8 + 4];
        float a0 = av[0][kk], a1 = av[1][kk], a2 = av[2][kk], a3 = av[3][kk];
#pragma unroll
        for (int j = 0; j < 8; ++j) {
          acc[0][j] = fmaf(a0, bv[j], acc[0][j]);
          acc[1][j] = fmaf(a1, bv[j], acc[1][j]);
          acc[2][j] = fmaf(a2, bv[j], acc[2][j]);
          acc[3][j] = fmaf(a3, bv[j], acc[3][j]);
        }
      }
    }
    __syncthreads();
  }
  // scatter C tile to LDS [t][c] (stride 132), then LIF scan per column
  float* Cl = smem;
#pragma unroll
  for (int i = 0; i < 4; ++i) {
    *(float4*)&Cl[(mq * 4 + i) * 132 + ng * 8] =
        make_float4(acc[i][0], acc[i][1], acc[i][2], acc[i][3]);
    *(float4*)&Cl[(mq * 4 + i) * 132 + ng * 8 + 4] =
        make_float4(acc[i][4], acc[i][5], acc[i][6], acc[i][7]);
  }
  __syncthreads();
  if (threadIdx.x < 128) {
    const int c = threadIdx.x;
    float v = 0.f;
    for (int t = 0; t < 64; ++t) {
      float pre = Cl[t * 132 + c];
      {
#pragma clang fp contract(off)
        float dlt = (pre - v) * 0.5f;  // v + (c-v)/tau, tau=2 (exact /2)
        v = v + dlt;
      }
      bool s = (v >= 1.0f);
      size_t orow = (size_t)(t * 4096 + bn);
      if (GATE) {
        float g = gate[orow * 128 + c];
        ((float*)outp)[orow * 128 + c] = s ? 0.f : g;  // g*(1-s) exact
      } else {
        ((unsigned short*)outp)[orow * NW + c0 + c] =
            s ? (unsigned short)0x3F80 : (unsigned short)0;  // bf16 1.0 / 0.0
      }
      v = s ? 0.f : v;  // hard reset
    }
  }
}

// ---------------------------------------------------------------------------
// W2 GEMM via MFMA (pilot): pre = sh(spikes,{0,1} bf16-exact) @ W2.
// W2 = hi+mid+lo exact bf16 planes -> 3 chained MFMAs per k-step; error class
// identical to reordered fp32 accumulation. A staged in LDS (64x256 bf16,
// stride 264 shorts); B-frags read direct from global (shared across all
// blocks -> L1/L2-hot). Wave w owns t-rows [w*16,w*16+16), all 128 c.
// LIF + gate epilogue identical to k_gemm_lif's GATE path.
// ---------------------------------------------------------------------------
__global__ __launch_bounds__(256) void k_w2_mfma(
    const unsigned short* __restrict__ sh, const unsigned short* __restrict__ Wt,
    const float* __restrict__ gate, float* __restrict__ out) {
  __shared__ unsigned short Asl[64 * 264];  // 33792 B -> 4 blocks/CU
  const int bn = blockIdx.x;
  {  // stage A spikes 64x256 bf16, coalesced 512B per row
    const int k8 = threadIdx.x & 31, tq = threadIdx.x >> 5;
#pragma unroll
    for (int p = 0; p < 8; ++p) {
      int t = p * 8 + tq;
      const uint4 v = *(const uint4*)&sh[(size_t)(t * 4096 + bn) * 256 + k8 * 8];
      *(uint4*)&Asl[t * 264 + k8 * 8] = v;
    }
  }
  __syncthreads();
  const int lane = threadIdx.x & 63, w = threadIdx.x >> 6;
  const int l15 = lane & 15, l4 = lane >> 4;
  bf16x8 af[8];  // A-frags: row w*16+l15, k = ks*32 + l4*8 .. +8
#pragma unroll
  for (int ks = 0; ks < 8; ++ks)
    af[ks] = *(const bf16x8*)&Asl[(w * 16 + l15) * 264 + ks * 32 + l4 * 8];
  const unsigned short* Bh = Wt;
  const unsigned short* Bm = Wt + 32768;
  const unsigned short* Blo = Wt + 65536;
  f32x4 acc[8];
#pragma unroll
  for (int ct = 0; ct < 8; ++ct) {
    f32x4 c = {0.f, 0.f, 0.f, 0.f};
    const int boff = (ct * 16 + l15) * 256 + l4 * 8;
#pragma unroll
    for (int ks = 0; ks < 8; ++ks) {
      bf16x8 bl = *(const bf16x8*)&Blo[boff + ks * 32];
      bf16x8 bm = *(const bf16x8*)&Bm[boff + ks * 32];
      bf16x8 bh = *(const bf16x8*)&Bh[boff + ks * 32];
      c = __builtin_amdgcn_mfma_f32_16x16x32_bf16(af[ks], bl, c, 0, 0, 0);
      c = __builtin_amdgcn_mfma_f32_16x16x32_bf16(af[ks], bm, c, 0, 0, 0);
      c = __builtin_amdgcn_mfma_f32_16x16x32_bf16(af[ks], bh, c, 0, 0, 0);
    }
    acc[ct] = c;
  }
  // scatter C to LDS [t][c] stride 132 (reuse Asl; waves write own rows only,
  // and each write data-depends on all of this wave's A-frag reads)
  float* Cl = (float*)Asl;
#pragma unroll
  for (int ct = 0; ct < 8; ++ct)
#pragma unroll
    for (int r = 0; r < 4; ++r)
      Cl[(w * 16 + l4 * 4 + r) * 132 + ct * 16 + l15] = acc[ct][r];
  __syncthreads();
  if (threadIdx.x < 128) {
    const int c = threadIdx.x;
    float v = 0.f;
    for (int t = 0; t < 64; ++t) {
      float pre = Cl[t * 132 + c];
      {
#pragma clang fp contract(off)
        float dlt = (pre - v) * 0.5f;  // v + (c-v)/tau, tau=2 (exact /2)
        v = v + dlt;
      }
      bool s = (v >= 1.0f);
      size_t orow = (size_t)(t * 4096 + bn);
      float g = gate[orow * 128 + c];
      out[orow * 128 + c] = s ? 0.f : g;  // g*(1-s) exact
      v = s ? 0.f : v;  // hard reset
    }
  }
}

// ---------------------------------------------------------------------------
// Spiking 2-head attention per (t,b):  S = q k^T * 0.125 ; O = S v. No softmax.
// Exact in bf16 MFMA: spikes in {0,1}; S integer<=64 (bf16-exact after *1/8);
// O = multiples of 1/8 <= 512 (fp32-exact). Wave w owns n-rows [w*16,w*16+16).
// ---------------------------------------------------------------------------
__global__ __launch_bounds__(256) void k_attn(
    const unsigned short* __restrict__ q, const unsigned short* __restrict__ kk,
    const unsigned short* __restrict__ vv, float* __restrict__ o) {
  __shared__ unsigned short ql[64 * 136];  // [n][d] bf16 bits
  __shared__ unsigned short kl[64 * 136];
  __shared__ unsigned short vt[128 * 72];  // [d][m] (v transposed)
  __shared__ unsigned short sl[64 * 72];   // S' [n][m] per head (reused)
  const size_t base = (size_t)blockIdx.x * 8192;
#pragma unroll
  for (int i = 0; i < 4; ++i) {
    int idx8 = threadIdx.x + i * 256;     // 1024 x 8-elem chunks
    int n = idx8 >> 4, d8 = (idx8 & 15) * 8;
    uint4 pq = *(const uint4*)&q[base + n * 128 + d8];
    uint4 pk = *(const uint4*)&kk[base + n * 128 + d8];
    *(uint4*)&ql[n * 136 + d8] = pq;
    *(uint4*)&kl[n * 136 + d8] = pk;
    uint4 pv = *(const uint4*)&vv[base + n * 128 + d8];
    unsigned short e[8] = {
        (unsigned short)(pv.x & 0xFFFF), (unsigned short)(pv.x >> 16),
        (unsigned short)(pv.y & 0xFFFF), (unsigned short)(pv.y >> 16),
        (unsigned short)(pv.z & 0xFFFF), (unsigned short)(pv.z >> 16),
        (unsigned short)(pv.w & 0xFFFF), (unsigned short)(pv.w >> 16)};
#pragma unroll
    for (int j = 0; j < 8; ++j) vt[(d8 + j) * 72 + n] = e[j];
  }
  __syncthreads();
  const int lane = threadIdx.x & 63;
  const int w = threadIdx.x >> 6;          // wave id = n-tile (ti)
  const int l15 = lane & 15, l4 = lane >> 4;
  for (int h = 0; h < 2; ++h) {
    // phase 1: S tiles (ti=w, tj=0..3), K = dh = 64 (2 MFMA k-steps)
    bf16x8 af0 = *(const bf16x8*)&ql[(w * 16 + l15) * 136 + h * 64 + l4 * 8];
    bf16x8 af1 = *(const bf16x8*)&ql[(w * 16 + l15) * 136 + h * 64 + 32 + l4 * 8];
#pragma unroll
    for (int tj = 0; tj < 4; ++tj) {
      f32x4 c = {0.f, 0.f, 0.f, 0.f};
      bf16x8 b0 = *(const bf16x8*)&kl[(tj * 16 + l15) * 136 + h * 64 + l4 * 8];
      c = __builtin_amdgcn_mfma_f32_16x16x32_bf16(af0, b0, c, 0, 0, 0);
      bf16x8 b1 = *(const bf16x8*)&kl[(tj * 16 + l15) * 136 + h * 64 + 32 + l4 * 8];
      c = __builtin_amdgcn_mfma_f32_16x16x32_bf16(af1, b1, c, 0, 0, 0);
#pragma unroll
      for (int r = 0; r < 4; ++r) {
        float sp = c[r] * 0.125f;  // exact; low 16 mantissa bits are zero
        sl[(w * 16 + l4 * 4 + r) * 72 + tj * 16 + l15] =
            (unsigned short)(__float_as_uint(sp) >> 16);
      }
    }
    __syncthreads();
    // phase 2: O tiles (ti=w, tj over dh), K = m = 64
    bf16x8 a20 = *(const bf16x8*)&sl[(w * 16 + l15) * 72 + l4 * 8];
    bf16x8 a21 = *(const bf16x8*)&sl[(w * 16 + l15) * 72 + 32 + l4 * 8];
#pragma unroll
    for (int tj = 0; tj < 4; ++tj) {
      f32x4 c = {0.f, 0.f, 0.f, 0.f};
      bf16x8 b0 = *(const bf16x8*)&vt[(h * 64 + tj * 16 + l15) * 72 + l4 * 8];
      c = __builtin_amdgcn_mfma_f32_16x16x32_bf16(a20, b0, c, 0, 0, 0);
      bf16x8 b1 = *(const bf16x8*)&vt[(h * 64 + tj * 16 + l15) * 72 + 32 + l4 * 8];
      c = __builtin_amdgcn_mfma_f32_16x16x32_bf16(a21, b1, c, 0, 0, 0);
#pragma unroll
      for (int r = 0; r < 4; ++r)
        o[base + (size_t)(w * 16 + l4 * 4 + r) * 128 + h * 64 + tj * 16 + l15] = c[r];
    }
    __syncthreads();  // sl reused by next head
  }
}

// ---------------------------------------------------------------------------
extern "C" void kernel_launch(void* const* d_in, const int* in_sizes, int n_in,
                              void* d_out, int out_size, void* d_ws, size_t ws_size,
                              hipStream_t stream) {
  const float* x  = (const float*)d_in[0];
  const float* mx = (const float*)d_in[1];
  const float* Wq = (const float*)d_in[2];
  const float* Wk = (const float*)d_in[3];
  const float* Wv = (const float*)d_in[4];
  const float* Wo = (const float*)d_in[5];
  const float* W1 = (const float*)d_in[6];
  const float* W2 = (const float*)d_in[7];
  float* out = (float*)d_out;

  // workspace layout (~470 MB):
  char* w = (char*)d_ws;
  float* G   = (float*)w;                                   // 16 KB (pad 64K)
  float* xlp = (float*)(w + 65536);                         // 134 MB, later o
  float* x2  = (float*)(w + 65536 + 134217728ull);          // 134 MB
  unsigned short* sq = (unsigned short*)(w + 65536 + 268435456ull);  // 67 MB
  unsigned short* sk = sq + 33554432ull;                    // 67 MB
  unsigned short* sv = sk + 33554432ull;                    // 67 MB
  unsigned short* sh = sq;  // mlp hidden spikes overlay sq+sk (134 MB)
  unsigned short* Wt = sv;  // W2 bf16 planes overlay sv (dead after attn)

  k_gram<<<64, 64, 0, stream>>>(G);
  k_lowpass<<<4096, 256, 0, stream>>>(x, mx, G, xlp);
  // q from x; k,v from lowpassed memory stream
  k_gemm_lif<128, false, false><<<dim3(4096, 1), 256, 0, stream>>>(x,   Wq, 128, nullptr, sq);
  k_gemm_lif<128, false, false><<<dim3(4096, 1), 256, 0, stream>>>(xlp, Wk, 128, nullptr, sk);
  k_gemm_lif<128, false, false><<<dim3(4096, 1), 256, 0, stream>>>(xlp, Wv, 128, nullptr, sv);
  k_attn<<<4096, 256, 0, stream>>>(sq, sk, sv, xlp);  // o overwrites xlp
  k_prep_w2<<<128, 256, 0, stream>>>(W2, Wt);         // sv dead now
  // attn_spk = lif(o @ Wo); x2 = x * (1 - attn_spk)
  k_gemm_lif<128, false, true ><<<dim3(4096, 1), 256, 0, stream>>>(xlp, Wo, 128, x, x2);
  // mlp: h = lif(x2 @ W1) (HID=256 -> grid.y=2); out = x2 * (1 - lif(h @ W2))
  k_gemm_lif<128, false, false><<<dim3(4096, 2), 256, 0, stream>>>(x2, W1, 256, nullptr, sh);
  k_w2_mfma<<<4096, 256, 0, stream>>>(sh, Wt, x2, out);
}

// Round 4
// 1174.191 us; speedup vs baseline: 1.3311x; 1.2889x over previous
//
#include <hip/hip_runtime.h>
#include <hip/hip_bf16.h>
#include <math.h>

// Problem dims (fixed)
#define TT   64
#define BBATCH 64
#define NTOK 64
#define DDIM 128
#define HIDN 256
#define BN   4096     // BBATCH*NTOK

typedef short bf16x8 __attribute__((ext_vector_type(8)));
typedef float f32x4  __attribute__((ext_vector_type(4)));

// ---------------------------------------------------------------------------
// G = C_low^T C_low : symmetric 64x64 Gram of the first 16 orthonormal DCT-II
// rows. lowpass_time(x) == G @ x along time.
// ---------------------------------------------------------------------------
__global__ void k_gram(float* __restrict__ G) {
  int s = blockIdx.x, t = threadIdx.x;
  double acc = 0.0;
  for (int k = 0; k < 16; ++k) {
    double ct, cs;
    if (k == 0) { ct = 0.125; cs = 0.125; }  // sqrt(1/64)
    else {
      const double f = 0.17677669529663687;  // sqrt(2/64)
      ct = cos(M_PI * (t + 0.5) * k / 64.0) * f;
      cs = cos(M_PI * (s + 0.5) * k / 64.0) * f;
    }
    acc += ct * cs;
  }
  G[s * 64 + t] = (float)acc;
}

// ---------------------------------------------------------------------------
// Exact 3-way bf16 split of a weight matrix, stored transposed [p][c][k].
//   w = hi + mid + lo + r3, |r3| <= 2^-24 |w| (RNE splits, exact residuals).
// ---------------------------------------------------------------------------
__global__ void k_prep(const float* __restrict__ W, unsigned short* __restrict__ Wt,
                       const int K, const int N) {
  int idx = blockIdx.x * 256 + threadIdx.x;  // k*N + c
  if (idx >= K * N) return;
  int k = idx / N, c = idx - k * N;
  float w = W[idx];
  unsigned uw = __float_as_uint(w);
  unsigned uh = (uw + 0x7FFF + ((uw >> 16) & 1)) & 0xFFFF0000u;
  float r1 = w - __uint_as_float(uh);
  unsigned ur = __float_as_uint(r1);
  unsigned um = (ur + 0x7FFF + ((ur >> 16) & 1)) & 0xFFFF0000u;
  float r2 = r1 - __uint_as_float(um);
  unsigned uv = __float_as_uint(r2);
  unsigned ul = (uv + 0x7FFF + ((uv >> 16) & 1)) & 0xFFFF0000u;
  size_t PS = (size_t)K * N;
  Wt[0 * PS + (size_t)c * K + k] = (unsigned short)(uh >> 16);
  Wt[1 * PS + (size_t)c * K + k] = (unsigned short)(um >> 16);
  Wt[2 * PS + (size_t)c * K + k] = (unsigned short)(ul >> 16);
}

// ---------------------------------------------------------------------------
// k_lowpass v2: xlp tile (64t x 128d) = G(64x64) @ m2(64s x 128d) per (b,n)
// block (proven r2: dropped out of top-5). fp32 FMA inner loop, no SMEM in
// hot loop, XOR-quad-swizzled G tile.
// ---------------------------------------------------------------------------
__global__ __launch_bounds__(256) void k_lowpass(
    const float* __restrict__ x, const float* __restrict__ mx,
    const float* __restrict__ G, float* __restrict__ xlp) {
  __shared__ float smem[64 * 64 + 64 * 128];  // 49152 B -> 3 blocks/CU
  float* Al = smem;            // G [t][s] swizzled, stride 64
  float* Bl = smem + 64 * 64;  // m2 [s][d], stride 128
  const int bn = blockIdx.x;
  const int b = bn >> 6, n = bn & 63;
  const float* mxs = mx + (size_t)(n * 64 + b) * 8192;  // (n,b) slab, contiguous
  {  // stage G: 4 float4/thread, store-side swizzle
    const int q = threadIdx.x & 15, tq = threadIdx.x >> 4;
#pragma unroll
    for (int p = 0; p < 4; ++p) {
      int t = p * 16 + tq;
      const float4 v = *(const float4*)&G[t * 64 + q * 4];
      *(float4*)&Al[t * 64 + 4 * (q ^ ((t >> 2) & 7))] = v;
    }
  }
#pragma unroll
  for (int i = 0; i < 8; ++i) {  // stage m2 = x * (.05mx+.95mx)
    int idx4 = threadIdx.x + i * 256;          // 0..2047 float4s
    int s = idx4 >> 5, dq = (idx4 & 31) * 4;
    const float4 xv = *(const float4*)&x[(size_t)(s * 4096 + bn) * 128 + dq];
    const float4 mv = *(const float4*)&mxs[idx4 * 4];
    float4 r;
    {
#pragma clang fp contract(off)
      // replicate reference rounding: fl(fl(.05m)+fl(.95m)) then * x
      r.x = xv.x * (0.05f * mv.x + 0.95f * mv.x);
      r.y = xv.y * (0.05f * mv.y + 0.95f * mv.y);
      r.z = xv.z * (0.05f * mv.z + 0.95f * mv.z);
      r.w = xv.w * (0.05f * mv.w + 0.95f * mv.w);
    }
    *(float4*)&Bl[s * 128 + dq] = r;
  }
  __syncthreads();
  const int mq = threadIdx.x & 15;   // t-quad: rows mq*4..mq*4+3
  const int ng = threadIdx.x >> 4;   // col-octet: cols ng*8..ng*8+7
  float acc[4][8];
#pragma unroll
  for (int i = 0; i < 4; ++i)
#pragma unroll
    for (int j = 0; j < 8; ++j) acc[i][j] = 0.f;
  const int sw = mq & 7;
#pragma unroll 2
  for (int kq = 0; kq < 16; ++kq) {
    float4 av[4];
#pragma unroll
    for (int i = 0; i < 4; ++i)
      av[i] = *(const float4*)&Al[(mq * 4 + i) * 64 + 4 * (kq ^ sw)];
#pragma unroll
    for (int kk = 0; kk < 4; ++kk) {
      float bv[8];
      *(float4*)&bv[0] = *(const float4*)&Bl[(kq * 4 + kk) * 128 + ng * 8];
      *(float4*)&bv[4] = *(const float4*)&Bl[(kq * 4 + kk) * 128 + ng * 8 + 4];
      float a0 = av[0][kk], a1 = av[1][kk], a2 = av[2][kk], a3 = av[3][kk];
#pragma unroll
      for (int j = 0; j < 8; ++j) {
        acc[0][j] = fmaf(a0, bv[j], acc[0][j]);
        acc[1][j] = fmaf(a1, bv[j], acc[1][j]);
        acc[2][j] = fmaf(a2, bv[j], acc[2][j]);
        acc[3][j] = fmaf(a3, bv[j], acc[3][j]);
      }
    }
  }
#pragma unroll
  for (int i = 0; i < 4; ++i) {  // direct store, coalesced per (t,bn) row
    int t = mq * 4 + i;
    size_t row = (size_t)(t * 4096 + bn) * 128;
    *(float4*)&xlp[row + ng * 8] =
        make_float4(acc[i][0], acc[i][1], acc[i][2], acc[i][3]);
    *(float4*)&xlp[row + ng * 8 + 4] =
        make_float4(acc[i][4], acc[i][5], acc[i][6], acc[i][7]);
  }
}

// ---------------------------------------------------------------------------
// Unified MFMA GEMM + LIF (+ gate).  pre[t][c] = A[(t,b,n)][:] . W[:][c0+c].
// ATYPE 0: A fp32, split per-chunk into 3 bf16 planes; 6-term product
//          (hi*{hi,mid,lo} + mid*{hi,mid} + lo*hi); dropped terms ~2^-24 rel.
// ATYPE 1: A bf16 spikes {0,1} (exact); 3-term (one per B plane).
// LDS layout: 16-B cells, cell index (q*NROWS + row) where q = k-octet (8
// halfs) within the 32-k chunk. Frag read phase (16 lanes, fixed l4=q):
// 16 consecutive cells = 256 B -> every bank exactly 2x = conflict-free.
// B: 3 planes x 128 cols staged per chunk (24 KB); A: 3x64 (12 KB) / 64 rows.
// ---------------------------------------------------------------------------
template <int KDIM, int ATYPE, bool GATE>
__global__ __launch_bounds__(256, 4) void k_mfma_lif(
    const void* __restrict__ Ap, const unsigned short* __restrict__ Wt,
    const int NW, const float* __restrict__ gate, void* __restrict__ outp) {
  constexpr int ACELLS = (ATYPE == 1) ? 256 : 768;   // 16-B cells for A tile
  constexpr int RAW = (ACELLS + 1536) * 16;
  constexpr int SB = RAW < 33792 ? 33792 : RAW;      // epilogue needs 64*132*4
  __shared__ __attribute__((aligned(16))) char smem[SB];
  unsigned short* Asl = (unsigned short*)smem;
  unsigned short* Bl = (unsigned short*)(smem + ACELLS * 16);
  const int bn = blockIdx.x;
  const int c0 = blockIdx.y * 128;
  const int tid = threadIdx.x;
  const int lane = tid & 63, w = tid >> 6;
  const int l15 = lane & 15, l4 = lane >> 4;
  f32x4 acc[8];
#pragma unroll
  for (int i = 0; i < 8; ++i) acc[i] = (f32x4){0.f, 0.f, 0.f, 0.f};

  for (int kc = 0; kc < KDIM; kc += 32) {
    // ---- stage A chunk (64 t x 32 k) ----
    {
      const int t = tid >> 2, q = tid & 3;
      if (ATYPE == 1) {
        const uint4 v = *(const uint4*)&((const unsigned short*)Ap)[
            (size_t)(t * 4096 + bn) * KDIM + kc + q * 8];
        *(uint4*)&Asl[(q * 64 + t) * 8] = v;
      } else {
        const float* arow =
            (const float*)Ap + (size_t)(t * 4096 + bn) * KDIM + kc + q * 8;
        float e[8];
        *(float4*)&e[0] = *(const float4*)&arow[0];
        *(float4*)&e[4] = *(const float4*)&arow[4];
        unsigned short hh[8], mm[8], ll[8];
#pragma unroll
        for (int j = 0; j < 8; ++j) {
          float wv = e[j];
          unsigned uw = __float_as_uint(wv);
          unsigned uh = (uw + 0x7FFF + ((uw >> 16) & 1)) & 0xFFFF0000u;
          float r1 = wv - __uint_as_float(uh);      // exact (Sterbenz)
          unsigned ur = __float_as_uint(r1);
          unsigned um = (ur + 0x7FFF + ((ur >> 16) & 1)) & 0xFFFF0000u;
          float r2 = r1 - __uint_as_float(um);      // exact
          unsigned uv2 = __float_as_uint(r2);
          unsigned ul = (uv2 + 0x7FFF + ((uv2 >> 16) & 1)) & 0xFFFF0000u;
          hh[j] = (unsigned short)(uh >> 16);
          mm[j] = (unsigned short)(um >> 16);
          ll[j] = (unsigned short)(ul >> 16);
        }
        *(uint4*)&Asl[(q * 192 + 0 * 64 + t) * 8] = *(uint4*)hh;
        *(uint4*)&Asl[(q * 192 + 1 * 64 + t) * 8] = *(uint4*)mm;
        *(uint4*)&Asl[(q * 192 + 2 * 64 + t) * 8] = *(uint4*)ll;
      }
    }
    // ---- stage B chunk: 3 planes x 128 cols x 32 k = 1536 cells ----
#pragma unroll
    for (int i = 0; i < 6; ++i) {
      int idx = i * 256 + tid;
      int row = idx >> 2, q = idx & 3;  // row = p*128 + c
      int p = row >> 7, c = row & 127;
      const uint4 v = *(const uint4*)&Wt[((size_t)p * NW + c0 + c) * KDIM + kc + q * 8];
      *(uint4*)&Bl[(q * 384 + row) * 8] = v;
    }
    __syncthreads();
    // ---- MFMA: 8 independent ct-chains ----
    bf16x8 af[(ATYPE == 1) ? 1 : 3];
    if (ATYPE == 1) {
      af[0] = *(const bf16x8*)&Asl[(l4 * 64 + w * 16 + l15) * 8];
    } else {
#pragma unroll
      for (int p = 0; p < 3; ++p)
        af[p] = *(const bf16x8*)&Asl[(l4 * 192 + p * 64 + w * 16 + l15) * 8];
    }
    constexpr int NT = (ATYPE == 1) ? 3 : 6;
    const int TPA[6] = {0, 0, 0, 1, 1, 2};
    const int TPB[6] = {0, 1, 2, 0, 1, 0};
#pragma unroll
    for (int tm = 0; tm < NT; ++tm) {
      const int pa = (ATYPE == 1) ? 0 : TPA[tm];
      const int pb = (ATYPE == 1) ? tm : TPB[tm];
#pragma unroll
      for (int ct = 0; ct < 8; ++ct) {
        bf16x8 bfr = *(const bf16x8*)&Bl[(l4 * 384 + pb * 128 + ct * 16 + l15) * 8];
        acc[ct] = __builtin_amdgcn_mfma_f32_16x16x32_bf16(af[pa], bfr, acc[ct], 0, 0, 0);
      }
    }
    __syncthreads();
  }
  // ---- C scatter (verified v1 mapping: row = w*16+l4*4+r, col = ct*16+l15) ----
  float* Cl = (float*)smem;
#pragma unroll
  for (int ct = 0; ct < 8; ++ct)
#pragma unroll
    for (int r = 0; r < 4; ++r)
      Cl[(w * 16 + l4 * 4 + r) * 132 + ct * 16 + l15] = acc[ct][r];
  __syncthreads();
  if (tid < 128) {
    const int c = tid;
    float v = 0.f;
    for (int t = 0; t < 64; ++t) {
      float pre = Cl[t * 132 + c];
      {
#pragma clang fp contract(off)
        float dlt = (pre - v) * 0.5f;  // v + (c-v)/tau, tau=2 (exact /2)
        v = v + dlt;
      }
      bool s = (v >= 1.0f);
      size_t orow = (size_t)(t * 4096 + bn);
      if (GATE) {
        float g = gate[orow * 128 + c];
        ((float*)outp)[orow * 128 + c] = s ? 0.f : g;  // g*(1-s) exact
      } else {
        ((unsigned short*)outp)[orow * NW + c0 + c] =
            s ? (unsigned short)0x3F80 : (unsigned short)0;  // bf16 1.0 / 0.0
      }
      v = s ? 0.f : v;  // hard reset
    }
  }
}

// ---------------------------------------------------------------------------
// Spiking 2-head attention per (t,b):  S = q k^T * 0.125 ; O = S v. No softmax.
// Exact in bf16 MFMA: spikes in {0,1}; S integer<=64 (bf16-exact after *1/8);
// O = multiples of 1/8 <= 512 (fp32-exact). Wave w owns n-rows [w*16,w*16+16).
// ---------------------------------------------------------------------------
__global__ __launch_bounds__(256) void k_attn(
    const unsigned short* __restrict__ q, const unsigned short* __restrict__ kk,
    const unsigned short* __restrict__ vv, float* __restrict__ o) {
  __shared__ unsigned short ql[64 * 136];  // [n][d] bf16 bits
  __shared__ unsigned short kl[64 * 136];
  __shared__ unsigned short vt[128 * 72];  // [d][m] (v transposed)
  __shared__ unsigned short sl[64 * 72];   // S' [n][m] per head (reused)
  const size_t base = (size_t)blockIdx.x * 8192;
#pragma unroll
  for (int i = 0; i < 4; ++i) {
    int idx8 = threadIdx.x + i * 256;     // 1024 x 8-elem chunks
    int n = idx8 >> 4, d8 = (idx8 & 15) * 8;
    uint4 pq = *(const uint4*)&q[base + n * 128 + d8];
    uint4 pk = *(const uint4*)&kk[base + n * 128 + d8];
    *(uint4*)&ql[n * 136 + d8] = pq;
    *(uint4*)&kl[n * 136 + d8] = pk;
    uint4 pv = *(const uint4*)&vv[base + n * 128 + d8];
    unsigned short e[8] = {
        (unsigned short)(pv.x & 0xFFFF), (unsigned short)(pv.x >> 16),
        (unsigned short)(pv.y & 0xFFFF), (unsigned short)(pv.y >> 16),
        (unsigned short)(pv.z & 0xFFFF), (unsigned short)(pv.z >> 16),
        (unsigned short)(pv.w & 0xFFFF), (unsigned short)(pv.w >> 16)};
#pragma unroll
    for (int j = 0; j < 8; ++j) vt[(d8 + j) * 72 + n] = e[j];
  }
  __syncthreads();
  const int lane = threadIdx.x & 63;
  const int w = threadIdx.x >> 6;          // wave id = n-tile (ti)
  const int l15 = lane & 15, l4 = lane >> 4;
  for (int h = 0; h < 2; ++h) {
    bf16x8 af0 = *(const bf16x8*)&ql[(w * 16 + l15) * 136 + h * 64 + l4 * 8];
    bf16x8 af1 = *(const bf16x8*)&ql[(w * 16 + l15) * 136 + h * 64 + 32 + l4 * 8];
#pragma unroll
    for (int tj = 0; tj < 4; ++tj) {
      f32x4 c = {0.f, 0.f, 0.f, 0.f};
      bf16x8 b0 = *(const bf16x8*)&kl[(tj * 16 + l15) * 136 + h * 64 + l4 * 8];
      c = __builtin_amdgcn_mfma_f32_16x16x32_bf16(af0, b0, c, 0, 0, 0);
      bf16x8 b1 = *(const bf16x8*)&kl[(tj * 16 + l15) * 136 + h * 64 + 32 + l4 * 8];
      c = __builtin_amdgcn_mfma_f32_16x16x32_bf16(af1, b1, c, 0, 0, 0);
#pragma unroll
      for (int r = 0; r < 4; ++r) {
        float sp = c[r] * 0.125f;  // exact; low 16 mantissa bits are zero
        sl[(w * 16 + l4 * 4 + r) * 72 + tj * 16 + l15] =
            (unsigned short)(__float_as_uint(sp) >> 16);
      }
    }
    __syncthreads();
    bf16x8 a20 = *(const bf16x8*)&sl[(w * 16 + l15) * 72 + l4 * 8];
    bf16x8 a21 = *(const bf16x8*)&sl[(w * 16 + l15) * 72 + 32 + l4 * 8];
#pragma unroll
    for (int tj = 0; tj < 4; ++tj) {
      f32x4 c = {0.f, 0.f, 0.f, 0.f};
      bf16x8 b0 = *(const bf16x8*)&vt[(h * 64 + tj * 16 + l15) * 72 + l4 * 8];
      c = __builtin_amdgcn_mfma_f32_16x16x32_bf16(a20, b0, c, 0, 0, 0);
      bf16x8 b1 = *(const bf16x8*)&vt[(h * 64 + tj * 16 + l15) * 72 + 32 + l4 * 8];
      c = __builtin_amdgcn_mfma_f32_16x16x32_bf16(a21, b1, c, 0, 0, 0);
#pragma unroll
      for (int r = 0; r < 4; ++r)
        o[base + (size_t)(w * 16 + l4 * 4 + r) * 128 + h * 64 + tj * 16 + l15] = c[r];
    }
    __syncthreads();  // sl reused by next head
  }
}

// ---------------------------------------------------------------------------
extern "C" void kernel_launch(void* const* d_in, const int* in_sizes, int n_in,
                              void* d_out, int out_size, void* d_ws, size_t ws_size,
                              hipStream_t stream) {
  const float* x  = (const float*)d_in[0];
  const float* mx = (const float*)d_in[1];
  const float* Wq = (const float*)d_in[2];
  const float* Wk = (const float*)d_in[3];
  const float* Wv = (const float*)d_in[4];
  const float* Wo = (const float*)d_in[5];
  const float* W1 = (const float*)d_in[6];
  const float* W2 = (const float*)d_in[7];
  float* out = (float*)d_out;

  // workspace layout (~449 MiB):
  char* w = (char*)d_ws;
  float* G = (float*)w;                                  // 16 KB
  unsigned short* wtq = (unsigned short*)(w + 16384);    // 3*128*128 halfs
  unsigned short* wtk = wtq + 3 * 16384;
  unsigned short* wtv = wtk + 3 * 16384;
  unsigned short* wto = wtv + 3 * 16384;
  unsigned short* wt1 = wto + 3 * 16384;                 // 3*128*256 halfs
  unsigned short* wt2 = wt1 + 3 * 32768;                 // 3*256*128 halfs
  float* xlp = (float*)(w + 1048576);                    // 134 MB, later o
  float* x2  = (float*)(w + 1048576 + 134217728ull);     // 134 MB
  unsigned short* sq = (unsigned short*)(w + 1048576 + 268435456ull);  // 67 MB
  unsigned short* sk = sq + 33554432ull;                 // 67 MB
  unsigned short* sv = sk + 33554432ull;                 // 67 MB
  unsigned short* sh = sq;  // mlp hidden spikes overlay sq+sk (134 MB)

  k_gram<<<64, 64, 0, stream>>>(G);
  k_prep<<<64, 256, 0, stream>>>(Wq, wtq, 128, 128);
  k_prep<<<64, 256, 0, stream>>>(Wk, wtk, 128, 128);
  k_prep<<<64, 256, 0, stream>>>(Wv, wtv, 128, 128);
  k_prep<<<64, 256, 0, stream>>>(Wo, wto, 128, 128);
  k_prep<<<128, 256, 0, stream>>>(W1, wt1, 128, 256);
  k_prep<<<128, 256, 0, stream>>>(W2, wt2, 256, 128);
  k_lowpass<<<4096, 256, 0, stream>>>(x, mx, G, xlp);
  // q from x; k,v from lowpassed memory stream
  k_mfma_lif<128, 0, false><<<dim3(4096, 1), 256, 0, stream>>>(x,   wtq, 128, nullptr, sq);
  k_mfma_lif<128, 0, false><<<dim3(4096, 1), 256, 0, stream>>>(xlp, wtk, 128, nullptr, sk);
  k_mfma_lif<128, 0, false><<<dim3(4096, 1), 256, 0, stream>>>(xlp, wtv, 128, nullptr, sv);
  k_attn<<<4096, 256, 0, stream>>>(sq, sk, sv, xlp);  // o overwrites xlp
  // attn_spk = lif(o @ Wo); x2 = x * (1 - attn_spk)
  k_mfma_lif<128, 0, true ><<<dim3(4096, 1), 256, 0, stream>>>(xlp, wto, 128, x, x2);
  // mlp: h = lif(x2 @ W1) (HID=256 -> grid.y=2); out = x2 * (1 - lif(h @ W2))
  k_mfma_lif<128, 0, false><<<dim3(4096, 2), 256, 0, stream>>>(x2, wt1, 256, nullptr, sh);
  k_mfma_lif<256, 1, true ><<<dim3(4096, 1), 256, 0, stream>>>(sh, wt2, 128, x2, out);
}

// Round 5
// 1091.880 us; speedup vs baseline: 1.4315x; 1.0754x over previous
//
#include <hip/hip_runtime.h>
#include <hip/hip_bf16.h>
#include <math.h>

// Problem dims (fixed)
#define TT   64
#define BBATCH 64
#define NTOK 64
#define DDIM 128
#define HIDN 256
#define BN   4096     // BBATCH*NTOK

typedef short bf16x8 __attribute__((ext_vector_type(8)));
typedef float f32x4  __attribute__((ext_vector_type(4)));
typedef float f32x16 __attribute__((ext_vector_type(16)));

// ---------------------------------------------------------------------------
// G = C_low^T C_low : symmetric 64x64 Gram of the first 16 orthonormal DCT-II
// rows. lowpass_time(x) == G @ x along time.
// ---------------------------------------------------------------------------
__global__ void k_gram(float* __restrict__ G) {
  int s = blockIdx.x, t = threadIdx.x;
  double acc = 0.0;
  for (int k = 0; k < 16; ++k) {
    double ct, cs;
    if (k == 0) { ct = 0.125; cs = 0.125; }  // sqrt(1/64)
    else {
      const double f = 0.17677669529663687;  // sqrt(2/64)
      ct = cos(M_PI * (t + 0.5) * k / 64.0) * f;
      cs = cos(M_PI * (s + 0.5) * k / 64.0) * f;
    }
    acc += ct * cs;
  }
  G[s * 64 + t] = (float)acc;
}

// ---------------------------------------------------------------------------
// Exact 3-way bf16 split of a weight matrix, stored transposed [p][c][k].
//   w = hi + mid + lo + r3, |r3| <= 2^-24 |w| (RNE splits, exact residuals).
// ---------------------------------------------------------------------------
__global__ void k_prep(const float* __restrict__ W, unsigned short* __restrict__ Wt,
                       const int K, const int N) {
  int idx = blockIdx.x * 256 + threadIdx.x;  // k*N + c
  if (idx >= K * N) return;
  int k = idx / N, c = idx - k * N;
  float w = W[idx];
  unsigned uw = __float_as_uint(w);
  unsigned uh = (uw + 0x7FFF + ((uw >> 16) & 1)) & 0xFFFF0000u;
  float r1 = w - __uint_as_float(uh);
  unsigned ur = __float_as_uint(r1);
  unsigned um = (ur + 0x7FFF + ((ur >> 16) & 1)) & 0xFFFF0000u;
  float r2 = r1 - __uint_as_float(um);
  unsigned uv = __float_as_uint(r2);
  unsigned ul = (uv + 0x7FFF + ((uv >> 16) & 1)) & 0xFFFF0000u;
  size_t PS = (size_t)K * N;
  Wt[0 * PS + (size_t)c * K + k] = (unsigned short)(uh >> 16);
  Wt[1 * PS + (size_t)c * K + k] = (unsigned short)(um >> 16);
  Wt[2 * PS + (size_t)c * K + k] = (unsigned short)(ul >> 16);
}

// ---------------------------------------------------------------------------
// k_lowpass v2: xlp tile (64t x 128d) = G(64x64) @ m2(64s x 128d) per (b,n)
// block (proven r2). fp32 FMA inner loop, no SMEM in hot loop, XOR-quad-
// swizzled G tile.
// ---------------------------------------------------------------------------
__global__ __launch_bounds__(256) void k_lowpass(
    const float* __restrict__ x, const float* __restrict__ mx,
    const float* __restrict__ G, float* __restrict__ xlp) {
  __shared__ float smem[64 * 64 + 64 * 128];  // 49152 B -> 3 blocks/CU
  float* Al = smem;            // G [t][s] swizzled, stride 64
  float* Bl = smem + 64 * 64;  // m2 [s][d], stride 128
  const int bn = blockIdx.x;
  const int b = bn >> 6, n = bn & 63;
  const float* mxs = mx + (size_t)(n * 64 + b) * 8192;  // (n,b) slab, contiguous
  {  // stage G: 4 float4/thread, store-side swizzle
    const int q = threadIdx.x & 15, tq = threadIdx.x >> 4;
#pragma unroll
    for (int p = 0; p < 4; ++p) {
      int t = p * 16 + tq;
      const float4 v = *(const float4*)&G[t * 64 + q * 4];
      *(float4*)&Al[t * 64 + 4 * (q ^ ((t >> 2) & 7))] = v;
    }
  }
#pragma unroll
  for (int i = 0; i < 8; ++i) {  // stage m2 = x * (.05mx+.95mx)
    int idx4 = threadIdx.x + i * 256;          // 0..2047 float4s
    int s = idx4 >> 5, dq = (idx4 & 31) * 4;
    const float4 xv = *(const float4*)&x[(size_t)(s * 4096 + bn) * 128 + dq];
    const float4 mv = *(const float4*)&mxs[idx4 * 4];
    float4 r;
    {
#pragma clang fp contract(off)
      // replicate reference rounding: fl(fl(.05m)+fl(.95m)) then * x
      r.x = xv.x * (0.05f * mv.x + 0.95f * mv.x);
      r.y = xv.y * (0.05f * mv.y + 0.95f * mv.y);
      r.z = xv.z * (0.05f * mv.z + 0.95f * mv.z);
      r.w = xv.w * (0.05f * mv.w + 0.95f * mv.w);
    }
    *(float4*)&Bl[s * 128 + dq] = r;
  }
  __syncthreads();
  const int mq = threadIdx.x & 15;   // t-quad: rows mq*4..mq*4+3
  const int ng = threadIdx.x >> 4;   // col-octet: cols ng*8..ng*8+7
  float acc[4][8];
#pragma unroll
  for (int i = 0; i < 4; ++i)
#pragma unroll
    for (int j = 0; j < 8; ++j) acc[i][j] = 0.f;
  const int sw = mq & 7;
#pragma unroll 2
  for (int kq = 0; kq < 16; ++kq) {
    float4 av[4];
#pragma unroll
    for (int i = 0; i < 4; ++i)
      av[i] = *(const float4*)&Al[(mq * 4 + i) * 64 + 4 * (kq ^ sw)];
#pragma unroll
    for (int kk = 0; kk < 4; ++kk) {
      float bv[8];
      *(float4*)&bv[0] = *(const float4*)&Bl[(kq * 4 + kk) * 128 + ng * 8];
      *(float4*)&bv[4] = *(const float4*)&Bl[(kq * 4 + kk) * 128 + ng * 8 + 4];
      float a0 = av[0][kk], a1 = av[1][kk], a2 = av[2][kk], a3 = av[3][kk];
#pragma unroll
      for (int j = 0; j < 8; ++j) {
        acc[0][j] = fmaf(a0, bv[j], acc[0][j]);
        acc[1][j] = fmaf(a1, bv[j], acc[1][j]);
        acc[2][j] = fmaf(a2, bv[j], acc[2][j]);
        acc[3][j] = fmaf(a3, bv[j], acc[3][j]);
      }
    }
  }
#pragma unroll
  for (int i = 0; i < 4; ++i) {  // direct store, coalesced per (t,bn) row
    int t = mq * 4 + i;
    size_t row = (size_t)(t * 4096 + bn) * 128;
    *(float4*)&xlp[row + ng * 8] =
        make_float4(acc[i][0], acc[i][1], acc[i][2], acc[i][3]);
    *(float4*)&xlp[row + ng * 8 + 4] =
        make_float4(acc[i][4], acc[i][5], acc[i][6], acc[i][7]);
  }
}

// ---------------------------------------------------------------------------
// Unified MFMA GEMM + LIF (+ gate), v3: 32x32x16 MFMA (2x MACs per LDS byte
// vs 16x16x32 -- r4 showed the 16x16 variant was LDS-issue-bound: 51 b128
// frag reads/chunk/wave, 2.8e7 bank-conflict cycles).
//   pre[t][c] = A[(t,b,n)][:] . W[:][c0+c]
// ATYPE 0: A fp32, split per-chunk into 3 bf16 planes; 6-term product
//          (hi*{hi,mid,lo} + mid*{hi,mid} + lo*hi); dropped terms ~2^-24 rel.
// ATYPE 1: A bf16 spikes {0,1} (exact); 3-term (one per B plane).
// LDS cells (16 B): A cell = q*(3*64)+p*64+t  (ATYPE1: q*64+t), B cell =
// q*384+p*128+c, q = k-octet in chunk. Frag reads: 32-lane groups read 32
// consecutive cells (512 B) -> uniform 8 dwords/bank (intrinsic b128 cost).
// Wave w: row-tile rt=w>>1 (rows rt*32..), col-tiles cb=(w&1)*2, cb+1.
// Per chunk/wave: 6 A-frag + 12 B-frag b128 reads, 24 MFMA (vs 51 reads
// before). C/D map (m74/m101): col=lane&31, row=(reg&3)+8*(reg>>2)+4*(l>>5).
// ---------------------------------------------------------------------------
template <int KDIM, int ATYPE, bool GATE>
__global__ __launch_bounds__(256, 4) void k_mfma_lif(
    const void* __restrict__ Ap, const unsigned short* __restrict__ Wt,
    const int NW, const float* __restrict__ gate, void* __restrict__ outp) {
  constexpr int ACELLS = (ATYPE == 1) ? 256 : 768;   // 16-B cells for A tile
  constexpr int RAW = (ACELLS + 1536) * 16;
  constexpr int SB = RAW < 33792 ? 33792 : RAW;      // epilogue needs 64*132*4
  __shared__ __attribute__((aligned(16))) char smem[SB];
  unsigned short* Asl = (unsigned short*)smem;
  unsigned short* Bl = (unsigned short*)(smem + ACELLS * 16);
  const int bn = blockIdx.x;
  const int c0 = blockIdx.y * 128;
  const int tid = threadIdx.x;
  const int lane = tid & 63, w = tid >> 6;
  const int l31 = lane & 31, lh = lane >> 5;
  const int rt = w >> 1;          // row-tile: rows rt*32 .. rt*32+31
  const int cb = (w & 1) * 2;     // col-tiles cb, cb+1
  f32x16 acc0, acc1;
#pragma unroll
  for (int i = 0; i < 16; ++i) { acc0[i] = 0.f; acc1[i] = 0.f; }

  for (int kc = 0; kc < KDIM; kc += 32) {
    // ---- stage A chunk (64 t x 32 k) ----
    {
      const int t = tid >> 2, q = tid & 3;
      if (ATYPE == 1) {
        const uint4 v = *(const uint4*)&((const unsigned short*)Ap)[
            (size_t)(t * 4096 + bn) * KDIM + kc + q * 8];
        *(uint4*)&Asl[(q * 64 + t) * 8] = v;
      } else {
        const float* arow =
            (const float*)Ap + (size_t)(t * 4096 + bn) * KDIM + kc + q * 8;
        float e[8];
        *(float4*)&e[0] = *(const float4*)&arow[0];
        *(float4*)&e[4] = *(const float4*)&arow[4];
        unsigned short hh[8], mm[8], ll[8];
#pragma unroll
        for (int j = 0; j < 8; ++j) {
          float wv = e[j];
          unsigned uw = __float_as_uint(wv);
          unsigned uh = (uw + 0x7FFF + ((uw >> 16) & 1)) & 0xFFFF0000u;
          float r1 = wv - __uint_as_float(uh);      // exact (Sterbenz)
          unsigned ur = __float_as_uint(r1);
          unsigned um = (ur + 0x7FFF + ((ur >> 16) & 1)) & 0xFFFF0000u;
          float r2 = r1 - __uint_as_float(um);      // exact
          unsigned uv2 = __float_as_uint(r2);
          unsigned ul = (uv2 + 0x7FFF + ((uv2 >> 16) & 1)) & 0xFFFF0000u;
          hh[j] = (unsigned short)(uh >> 16);
          mm[j] = (unsigned short)(um >> 16);
          ll[j] = (unsigned short)(ul >> 16);
        }
        *(uint4*)&Asl[(q * 192 + 0 * 64 + t) * 8] = *(uint4*)hh;
        *(uint4*)&Asl[(q * 192 + 1 * 64 + t) * 8] = *(uint4*)mm;
        *(uint4*)&Asl[(q * 192 + 2 * 64 + t) * 8] = *(uint4*)ll;
      }
    }
    // ---- stage B chunk: 3 planes x 128 cols x 32 k = 1536 cells ----
#pragma unroll
    for (int i = 0; i < 6; ++i) {
      int idx = i * 256 + tid;
      int row = idx >> 2, q = idx & 3;  // row = p*128 + c
      int p = row >> 7, c = row & 127;
      const uint4 v = *(const uint4*)&Wt[((size_t)p * NW + c0 + c) * KDIM + kc + q * 8];
      *(uint4*)&Bl[(q * 384 + row) * 8] = v;
    }
    __syncthreads();
    // ---- MFMA: 2 k-steps of 32x32x16, two interleaved ct-chains ----
#pragma unroll
    for (int ks = 0; ks < 2; ++ks) {
      const int ko = ks * 2 + lh;  // k-octet for this lane-half
      bf16x8 a0, a1, a2;
      if (ATYPE == 1) {
        a0 = *(const bf16x8*)&Asl[(ko * 64 + rt * 32 + l31) * 8];
      } else {
        a0 = *(const bf16x8*)&Asl[(ko * 192 + 0 * 64 + rt * 32 + l31) * 8];
        a1 = *(const bf16x8*)&Asl[(ko * 192 + 1 * 64 + rt * 32 + l31) * 8];
        a2 = *(const bf16x8*)&Asl[(ko * 192 + 2 * 64 + rt * 32 + l31) * 8];
      }
      bf16x8 b0[2], b1[2], b2[2];
#pragma unroll
      for (int ci = 0; ci < 2; ++ci) {
        const int cc = (cb + ci) * 32 + l31;
        b0[ci] = *(const bf16x8*)&Bl[(ko * 384 + 0 * 128 + cc) * 8];
        b1[ci] = *(const bf16x8*)&Bl[(ko * 384 + 1 * 128 + cc) * 8];
        b2[ci] = *(const bf16x8*)&Bl[(ko * 384 + 2 * 128 + cc) * 8];
      }
      if (ATYPE == 1) {
        acc0 = __builtin_amdgcn_mfma_f32_32x32x16_bf16(a0, b0[0], acc0, 0, 0, 0);
        acc1 = __builtin_amdgcn_mfma_f32_32x32x16_bf16(a0, b0[1], acc1, 0, 0, 0);
        acc0 = __builtin_amdgcn_mfma_f32_32x32x16_bf16(a0, b1[0], acc0, 0, 0, 0);
        acc1 = __builtin_amdgcn_mfma_f32_32x32x16_bf16(a0, b1[1], acc1, 0, 0, 0);
        acc0 = __builtin_amdgcn_mfma_f32_32x32x16_bf16(a0, b2[0], acc0, 0, 0, 0);
        acc1 = __builtin_amdgcn_mfma_f32_32x32x16_bf16(a0, b2[1], acc1, 0, 0, 0);
      } else {
        acc0 = __builtin_amdgcn_mfma_f32_32x32x16_bf16(a0, b0[0], acc0, 0, 0, 0);
        acc1 = __builtin_amdgcn_mfma_f32_32x32x16_bf16(a0, b0[1], acc1, 0, 0, 0);
        acc0 = __builtin_amdgcn_mfma_f32_32x32x16_bf16(a0, b1[0], acc0, 0, 0, 0);
        acc1 = __builtin_amdgcn_mfma_f32_32x32x16_bf16(a0, b1[1], acc1, 0, 0, 0);
        acc0 = __builtin_amdgcn_mfma_f32_32x32x16_bf16(a0, b2[0], acc0, 0, 0, 0);
        acc1 = __builtin_amdgcn_mfma_f32_32x32x16_bf16(a0, b2[1], acc1, 0, 0, 0);
        acc0 = __builtin_amdgcn_mfma_f32_32x32x16_bf16(a1, b0[0], acc0, 0, 0, 0);
        acc1 = __builtin_amdgcn_mfma_f32_32x32x16_bf16(a1, b0[1], acc1, 0, 0, 0);
        acc0 = __builtin_amdgcn_mfma_f32_32x32x16_bf16(a1, b1[0], acc0, 0, 0, 0);
        acc1 = __builtin_amdgcn_mfma_f32_32x32x16_bf16(a1, b1[1], acc1, 0, 0, 0);
        acc0 = __builtin_amdgcn_mfma_f32_32x32x16_bf16(a2, b0[0], acc0, 0, 0, 0);
        acc1 = __builtin_amdgcn_mfma_f32_32x32x16_bf16(a2, b0[1], acc1, 0, 0, 0);
      }
    }
    __syncthreads();
  }
  // ---- C scatter: 32x32 C/D map col=l31, row=(reg&3)+8*(reg>>2)+4*lh ----
  float* Cl = (float*)smem;
#pragma unroll
  for (int reg = 0; reg < 16; ++reg) {
    int row32 = (reg & 3) + 8 * (reg >> 2) + 4 * lh;
    int t = rt * 32 + row32;
    Cl[t * 132 + (cb + 0) * 32 + l31] = acc0[reg];
    Cl[t * 132 + (cb + 1) * 32 + l31] = acc1[reg];
  }
  __syncthreads();
  if (tid < 128) {
    const int c = tid;
    float v = 0.f;
    for (int t = 0; t < 64; ++t) {
      float pre = Cl[t * 132 + c];
      {
#pragma clang fp contract(off)
        float dlt = (pre - v) * 0.5f;  // v + (c-v)/tau, tau=2 (exact /2)
        v = v + dlt;
      }
      bool s = (v >= 1.0f);
      size_t orow = (size_t)(t * 4096 + bn);
      if (GATE) {
        float g = gate[orow * 128 + c];
        ((float*)outp)[orow * 128 + c] = s ? 0.f : g;  // g*(1-s) exact
      } else {
        ((unsigned short*)outp)[orow * NW + c0 + c] =
            s ? (unsigned short)0x3F80 : (unsigned short)0;  // bf16 1.0 / 0.0
      }
      v = s ? 0.f : v;  // hard reset
    }
  }
}

// ---------------------------------------------------------------------------
// Spiking 2-head attention per (t,b):  S = q k^T * 0.125 ; O = S v. No softmax.
// Exact in bf16 MFMA: spikes in {0,1}; S integer<=64 (bf16-exact after *1/8);
// O = multiples of 1/8 <= 512 (fp32-exact). Wave w owns n-rows [w*16,w*16+16).
// ---------------------------------------------------------------------------
__global__ __launch_bounds__(256) void k_attn(
    const unsigned short* __restrict__ q, const unsigned short* __restrict__ kk,
    const unsigned short* __restrict__ vv, float* __restrict__ o) {
  __shared__ unsigned short ql[64 * 136];  // [n][d] bf16 bits
  __shared__ unsigned short kl[64 * 136];
  __shared__ unsigned short vt[128 * 72];  // [d][m] (v transposed)
  __shared__ unsigned short sl[64 * 72];   // S' [n][m] per head (reused)
  const size_t base = (size_t)blockIdx.x * 8192;
#pragma unroll
  for (int i = 0; i < 4; ++i) {
    int idx8 = threadIdx.x + i * 256;     // 1024 x 8-elem chunks
    int n = idx8 >> 4, d8 = (idx8 & 15) * 8;
    uint4 pq = *(const uint4*)&q[base + n * 128 + d8];
    uint4 pk = *(const uint4*)&kk[base + n * 128 + d8];
    *(uint4*)&ql[n * 136 + d8] = pq;
    *(uint4*)&kl[n * 136 + d8] = pk;
    uint4 pv = *(const uint4*)&vv[base + n * 128 + d8];
    unsigned short e[8] = {
        (unsigned short)(pv.x & 0xFFFF), (unsigned short)(pv.x >> 16),
        (unsigned short)(pv.y & 0xFFFF), (unsigned short)(pv.y >> 16),
        (unsigned short)(pv.z & 0xFFFF), (unsigned short)(pv.z >> 16),
        (unsigned short)(pv.w & 0xFFFF), (unsigned short)(pv.w >> 16)};
#pragma unroll
    for (int j = 0; j < 8; ++j) vt[(d8 + j) * 72 + n] = e[j];
  }
  __syncthreads();
  const int lane = threadIdx.x & 63;
  const int w = threadIdx.x >> 6;          // wave id = n-tile (ti)
  const int l15 = lane & 15, l4 = lane >> 4;
  for (int h = 0; h < 2; ++h) {
    bf16x8 af0 = *(const bf16x8*)&ql[(w * 16 + l15) * 136 + h * 64 + l4 * 8];
    bf16x8 af1 = *(const bf16x8*)&ql[(w * 16 + l15) * 136 + h * 64 + 32 + l4 * 8];
#pragma unroll
    for (int tj = 0; tj < 4; ++tj) {
      f32x4 c = {0.f, 0.f, 0.f, 0.f};
      bf16x8 b0 = *(const bf16x8*)&kl[(tj * 16 + l15) * 136 + h * 64 + l4 * 8];
      c = __builtin_amdgcn_mfma_f32_16x16x32_bf16(af0, b0, c, 0, 0, 0);
      bf16x8 b1 = *(const bf16x8*)&kl[(tj * 16 + l15) * 136 + h * 64 + 32 + l4 * 8];
      c = __builtin_amdgcn_mfma_f32_16x16x32_bf16(af1, b1, c, 0, 0, 0);
#pragma unroll
      for (int r = 0; r < 4; ++r) {
        float sp = c[r] * 0.125f;  // exact; low 16 mantissa bits are zero
        sl[(w * 16 + l4 * 4 + r) * 72 + tj * 16 + l15] =
            (unsigned short)(__float_as_uint(sp) >> 16);
      }
    }
    __syncthreads();
    bf16x8 a20 = *(const bf16x8*)&sl[(w * 16 + l15) * 72 + l4 * 8];
    bf16x8 a21 = *(const bf16x8*)&sl[(w * 16 + l15) * 72 + 32 + l4 * 8];
#pragma unroll
    for (int tj = 0; tj < 4; ++tj) {
      f32x4 c = {0.f, 0.f, 0.f, 0.f};
      bf16x8 b0 = *(const bf16x8*)&vt[(h * 64 + tj * 16 + l15) * 72 + l4 * 8];
      c = __builtin_amdgcn_mfma_f32_16x16x32_bf16(a20, b0, c, 0, 0, 0);
      bf16x8 b1 = *(const bf16x8*)&vt[(h * 64 + tj * 16 + l15) * 72 + 32 + l4 * 8];
      c = __builtin_amdgcn_mfma_f32_16x16x32_bf16(a21, b1, c, 0, 0, 0);
#pragma unroll
      for (int r = 0; r < 4; ++r)
        o[base + (size_t)(w * 16 + l4 * 4 + r) * 128 + h * 64 + tj * 16 + l15] = c[r];
    }
    __syncthreads();  // sl reused by next head
  }
}

// ---------------------------------------------------------------------------
extern "C" void kernel_launch(void* const* d_in, const int* in_sizes, int n_in,
                              void* d_out, int out_size, void* d_ws, size_t ws_size,
                              hipStream_t stream) {
  const float* x  = (const float*)d_in[0];
  const float* mx = (const float*)d_in[1];
  const float* Wq = (const float*)d_in[2];
  const float* Wk = (const float*)d_in[3];
  const float* Wv = (const float*)d_in[4];
  const float* Wo = (const float*)d_in[5];
  const float* W1 = (const float*)d_in[6];
  const float* W2 = (const float*)d_in[7];
  float* out = (float*)d_out;

  // workspace layout (~449 MiB):
  char* w = (char*)d_ws;
  float* G = (float*)w;                                  // 16 KB
  unsigned short* wtq = (unsigned short*)(w + 16384);    // 3*128*128 halfs
  unsigned short* wtk = wtq + 3 * 16384;
  unsigned short* wtv = wtk + 3 * 16384;
  unsigned short* wto = wtv + 3 * 16384;
  unsigned short* wt1 = wto + 3 * 16384;                 // 3*128*256 halfs
  unsigned short* wt2 = wt1 + 3 * 32768;                 // 3*256*128 halfs
  float* xlp = (float*)(w + 1048576);                    // 134 MB, later o
  float* x2  = (float*)(w + 1048576 + 134217728ull);     // 134 MB
  unsigned short* sq = (unsigned short*)(w + 1048576 + 268435456ull);  // 67 MB
  unsigned short* sk = sq + 33554432ull;                 // 67 MB
  unsigned short* sv = sk + 33554432ull;                 // 67 MB
  unsigned short* sh = sq;  // mlp hidden spikes overlay sq+sk (134 MB)

  k_gram<<<64, 64, 0, stream>>>(G);
  k_prep<<<64, 256, 0, stream>>>(Wq, wtq, 128, 128);
  k_prep<<<64, 256, 0, stream>>>(Wk, wtk, 128, 128);
  k_prep<<<64, 256, 0, stream>>>(Wv, wtv, 128, 128);
  k_prep<<<64, 256, 0, stream>>>(Wo, wto, 128, 128);
  k_prep<<<128, 256, 0, stream>>>(W1, wt1, 128, 256);
  k_prep<<<128, 256, 0, stream>>>(W2, wt2, 256, 128);
  k_lowpass<<<4096, 256, 0, stream>>>(x, mx, G, xlp);
  // q from x; k,v from lowpassed memory stream
  k_mfma_lif<128, 0, false><<<dim3(4096, 1), 256, 0, stream>>>(x,   wtq, 128, nullptr, sq);
  k_mfma_lif<128, 0, false><<<dim3(4096, 1), 256, 0, stream>>>(xlp, wtk, 128, nullptr, sk);
  k_mfma_lif<128, 0, false><<<dim3(4096, 1), 256, 0, stream>>>(xlp, wtv, 128, nullptr, sv);
  k_attn<<<4096, 256, 0, stream>>>(sq, sk, sv, xlp);  // o overwrites xlp
  // attn_spk = lif(o @ Wo); x2 = x * (1 - attn_spk)
  k_mfma_lif<128, 0, true ><<<dim3(4096, 1), 256, 0, stream>>>(xlp, wto, 128, x, x2);
  // mlp: h = lif(x2 @ W1) (HID=256 -> grid.y=2); out = x2 * (1 - lif(h @ W2))
  k_mfma_lif<128, 0, false><<<dim3(4096, 2), 256, 0, stream>>>(x2, wt1, 256, nullptr, sh);
  k_mfma_lif<256, 1, true ><<<dim3(4096, 1), 256, 0, stream>>>(sh, wt2, 128, x2, out);
}

// Round 6
// 1074.701 us; speedup vs baseline: 1.4544x; 1.0160x over previous
//
#include <hip/hip_runtime.h>
#include <hip/hip_bf16.h>
#include <math.h>

// Problem dims (fixed)
#define TT   64
#define BBATCH 64
#define NTOK 64
#define DDIM 128
#define HIDN 256
#define BN   4096     // BBATCH*NTOK

typedef short bf16x8 __attribute__((ext_vector_type(8)));
typedef float f32x4  __attribute__((ext_vector_type(4)));
typedef float f32x16 __attribute__((ext_vector_type(16)));

// ---------------------------------------------------------------------------
// G = C_low^T C_low : symmetric 64x64 Gram of the first 16 orthonormal DCT-II
// rows. lowpass_time(x) == G @ x along time.
// ---------------------------------------------------------------------------
__global__ void k_gram(float* __restrict__ G) {
  int s = blockIdx.x, t = threadIdx.x;
  double acc = 0.0;
  for (int k = 0; k < 16; ++k) {
    double ct, cs;
    if (k == 0) { ct = 0.125; cs = 0.125; }  // sqrt(1/64)
    else {
      const double f = 0.17677669529663687;  // sqrt(2/64)
      ct = cos(M_PI * (t + 0.5) * k / 64.0) * f;
      cs = cos(M_PI * (s + 0.5) * k / 64.0) * f;
    }
    acc += ct * cs;
  }
  G[s * 64 + t] = (float)acc;
}

// ---------------------------------------------------------------------------
// Exact 3-way bf16 split of a weight matrix, stored transposed [p][c][k].
//   w = hi + mid + lo + r3, |r3| <= 2^-24 |w| (RNE splits, exact residuals).
// ---------------------------------------------------------------------------
__global__ void k_prep(const float* __restrict__ W, unsigned short* __restrict__ Wt,
                       const int K, const int N) {
  int idx = blockIdx.x * 256 + threadIdx.x;  // k*N + c
  if (idx >= K * N) return;
  int k = idx / N, c = idx - k * N;
  float w = W[idx];
  unsigned uw = __float_as_uint(w);
  unsigned uh = (uw + 0x7FFF + ((uw >> 16) & 1)) & 0xFFFF0000u;
  float r1 = w - __uint_as_float(uh);
  unsigned ur = __float_as_uint(r1);
  unsigned um = (ur + 0x7FFF + ((ur >> 16) & 1)) & 0xFFFF0000u;
  float r2 = r1 - __uint_as_float(um);
  unsigned uv = __float_as_uint(r2);
  unsigned ul = (uv + 0x7FFF + ((uv >> 16) & 1)) & 0xFFFF0000u;
  size_t PS = (size_t)K * N;
  Wt[0 * PS + (size_t)c * K + k] = (unsigned short)(uh >> 16);
  Wt[1 * PS + (size_t)c * K + k] = (unsigned short)(um >> 16);
  Wt[2 * PS + (size_t)c * K + k] = (unsigned short)(ul >> 16);
}

// ---------------------------------------------------------------------------
// k_lowpass v2: xlp tile (64t x 128d) = G(64x64) @ m2(64s x 128d) per (b,n)
// block (proven r2). fp32 FMA inner loop, no SMEM in hot loop, XOR-quad-
// swizzled G tile.
// ---------------------------------------------------------------------------
__global__ __launch_bounds__(256) void k_lowpass(
    const float* __restrict__ x, const float* __restrict__ mx,
    const float* __restrict__ G, float* __restrict__ xlp) {
  __shared__ float smem[64 * 64 + 64 * 128];  // 49152 B -> 3 blocks/CU
  float* Al = smem;            // G [t][s] swizzled, stride 64
  float* Bl = smem + 64 * 64;  // m2 [s][d], stride 128
  const int bn = blockIdx.x;
  const int b = bn >> 6, n = bn & 63;
  const float* mxs = mx + (size_t)(n * 64 + b) * 8192;  // (n,b) slab, contiguous
  {  // stage G: 4 float4/thread, store-side swizzle
    const int q = threadIdx.x & 15, tq = threadIdx.x >> 4;
#pragma unroll
    for (int p = 0; p < 4; ++p) {
      int t = p * 16 + tq;
      const float4 v = *(const float4*)&G[t * 64 + q * 4];
      *(float4*)&Al[t * 64 + 4 * (q ^ ((t >> 2) & 7))] = v;
    }
  }
#pragma unroll
  for (int i = 0; i < 8; ++i) {  // stage m2 = x * (.05mx+.95mx)
    int idx4 = threadIdx.x + i * 256;          // 0..2047 float4s
    int s = idx4 >> 5, dq = (idx4 & 31) * 4;
    const float4 xv = *(const float4*)&x[(size_t)(s * 4096 + bn) * 128 + dq];
    const float4 mv = *(const float4*)&mxs[idx4 * 4];
    float4 r;
    {
#pragma clang fp contract(off)
      // replicate reference rounding: fl(fl(.05m)+fl(.95m)) then * x
      r.x = xv.x * (0.05f * mv.x + 0.95f * mv.x);
      r.y = xv.y * (0.05f * mv.y + 0.95f * mv.y);
      r.z = xv.z * (0.05f * mv.z + 0.95f * mv.z);
      r.w = xv.w * (0.05f * mv.w + 0.95f * mv.w);
    }
    *(float4*)&Bl[s * 128 + dq] = r;
  }
  __syncthreads();
  const int mq = threadIdx.x & 15;   // t-quad: rows mq*4..mq*4+3
  const int ng = threadIdx.x >> 4;   // col-octet: cols ng*8..ng*8+7
  float acc[4][8];
#pragma unroll
  for (int i = 0; i < 4; ++i)
#pragma unroll
    for (int j = 0; j < 8; ++j) acc[i][j] = 0.f;
  const int sw = mq & 7;
#pragma unroll 2
  for (int kq = 0; kq < 16; ++kq) {
    float4 av[4];
#pragma unroll
    for (int i = 0; i < 4; ++i)
      av[i] = *(const float4*)&Al[(mq * 4 + i) * 64 + 4 * (kq ^ sw)];
#pragma unroll
    for (int kk = 0; kk < 4; ++kk) {
      float bv[8];
      *(float4*)&bv[0] = *(const float4*)&Bl[(kq * 4 + kk) * 128 + ng * 8];
      *(float4*)&bv[4] = *(const float4*)&Bl[(kq * 4 + kk) * 128 + ng * 8 + 4];
      float a0 = av[0][kk], a1 = av[1][kk], a2 = av[2][kk], a3 = av[3][kk];
#pragma unroll
      for (int j = 0; j < 8; ++j) {
        acc[0][j] = fmaf(a0, bv[j], acc[0][j]);
        acc[1][j] = fmaf(a1, bv[j], acc[1][j]);
        acc[2][j] = fmaf(a2, bv[j], acc[2][j]);
        acc[3][j] = fmaf(a3, bv[j], acc[3][j]);
      }
    }
  }
#pragma unroll
  for (int i = 0; i < 4; ++i) {  // direct store, coalesced per (t,bn) row
    int t = mq * 4 + i;
    size_t row = (size_t)(t * 4096 + bn) * 128;
    *(float4*)&xlp[row + ng * 8] =
        make_float4(acc[i][0], acc[i][1], acc[i][2], acc[i][3]);
    *(float4*)&xlp[row + ng * 8 + 4] =
        make_float4(acc[i][4], acc[i][5], acc[i][6], acc[i][7]);
  }
}

// ---------------------------------------------------------------------------
// Unified MFMA GEMM + LIF (+ gate), v4: 32x32x16 MFMA + SKEWED LDS strides.
// r4/r5 both showed SQ_LDS_BANK_CONFLICT == 2.831e7 (identical despite the
// compute-phase rewrite) -> conflicts live in the STAGING WRITES: with cell
// strides q*192 / q*384 (== 0 mod 8 cells), lanes 0-3 (same t, q=0..3) hit
// one 4-bank group -> 4-way write conflict. Fix: plane stride == 4 mod 8
// cells (A: 196/octet, ATYPE1: 68; B: 388) -> every 16-lane phase covers
// each bank-group exactly 2x (uniform = intrinsic b128 floor, zero excess).
//   pre[t][c] = A[(t,b,n)][:] . W[:][c0+c]
// ATYPE 0: A fp32, split per-chunk into 3 bf16 planes; 6-term product.
// ATYPE 1: A bf16 spikes {0,1} (exact); 3-term.
// Wave w: row-tile rt=w>>1, col-tiles cb=(w&1)*2, cb+1.
// C/D map (m74/m101): col=lane&31, row=(reg&3)+8*(reg>>2)+4*(lane>>5).
// ---------------------------------------------------------------------------
template <int KDIM, int ATYPE, bool GATE>
__global__ __launch_bounds__(256, 4) void k_mfma_lif(
    const void* __restrict__ Ap, const unsigned short* __restrict__ Wt,
    const int NW, const float* __restrict__ gate, void* __restrict__ outp) {
  constexpr int AQ = (ATYPE == 1) ? 68 : 196;        // A cells per k-octet (skewed)
  constexpr int BQ = 388;                            // B cells per k-octet (skewed)
  constexpr int ACELLS = (ATYPE == 1) ? 272 : 784;   // 16-B cells for A tile
  constexpr int RAW = (ACELLS + 4 * BQ) * 16;
  constexpr int SB = RAW < 33792 ? 33792 : RAW;      // epilogue needs 64*132*4
  __shared__ __attribute__((aligned(16))) char smem[SB];
  unsigned short* Asl = (unsigned short*)smem;
  unsigned short* Bl = (unsigned short*)(smem + ACELLS * 16);
  const int bn = blockIdx.x;
  const int c0 = blockIdx.y * 128;
  const int tid = threadIdx.x;
  const int lane = tid & 63, w = tid >> 6;
  const int l31 = lane & 31, lh = lane >> 5;
  const int rt = w >> 1;          // row-tile: rows rt*32 .. rt*32+31
  const int cb = (w & 1) * 2;     // col-tiles cb, cb+1
  f32x16 acc0, acc1;
#pragma unroll
  for (int i = 0; i < 16; ++i) { acc0[i] = 0.f; acc1[i] = 0.f; }

  for (int kc = 0; kc < KDIM; kc += 32) {
    // ---- stage A chunk (64 t x 32 k) ----
    {
      const int t = tid >> 2, q = tid & 3;
      if (ATYPE == 1) {
        const uint4 v = *(const uint4*)&((const unsigned short*)Ap)[
            (size_t)(t * 4096 + bn) * KDIM + kc + q * 8];
        *(uint4*)&Asl[(q * AQ + t) * 8] = v;
      } else {
        const float* arow =
            (const float*)Ap + (size_t)(t * 4096 + bn) * KDIM + kc + q * 8;
        float e[8];
        *(float4*)&e[0] = *(const float4*)&arow[0];
        *(float4*)&e[4] = *(const float4*)&arow[4];
        unsigned short hh[8], mm[8], ll[8];
#pragma unroll
        for (int j = 0; j < 8; ++j) {
          float wv = e[j];
          unsigned uw = __float_as_uint(wv);
          unsigned uh = (uw + 0x7FFF + ((uw >> 16) & 1)) & 0xFFFF0000u;
          float r1 = wv - __uint_as_float(uh);      // exact (Sterbenz)
          unsigned ur = __float_as_uint(r1);
          unsigned um = (ur + 0x7FFF + ((ur >> 16) & 1)) & 0xFFFF0000u;
          float r2 = r1 - __uint_as_float(um);      // exact
          unsigned uv2 = __float_as_uint(r2);
          unsigned ul = (uv2 + 0x7FFF + ((uv2 >> 16) & 1)) & 0xFFFF0000u;
          hh[j] = (unsigned short)(uh >> 16);
          mm[j] = (unsigned short)(um >> 16);
          ll[j] = (unsigned short)(ul >> 16);
        }
        *(uint4*)&Asl[(q * AQ + 0 * 64 + t) * 8] = *(uint4*)hh;
        *(uint4*)&Asl[(q * AQ + 1 * 64 + t) * 8] = *(uint4*)mm;
        *(uint4*)&Asl[(q * AQ + 2 * 64 + t) * 8] = *(uint4*)ll;
      }
    }
    // ---- stage B chunk: 3 planes x 128 cols x 32 k ----
#pragma unroll
    for (int i = 0; i < 6; ++i) {
      int idx = i * 256 + tid;
      int row = idx >> 2, q = idx & 3;  // row = p*128 + c
      int p = row >> 7, c = row & 127;
      const uint4 v = *(const uint4*)&Wt[((size_t)p * NW + c0 + c) * KDIM + kc + q * 8];
      *(uint4*)&Bl[(q * BQ + row) * 8] = v;
    }
    __syncthreads();
    // ---- MFMA: 2 k-steps of 32x32x16, two interleaved ct-chains ----
#pragma unroll
    for (int ks = 0; ks < 2; ++ks) {
      const int ko = ks * 2 + lh;  // k-octet for this lane-half
      bf16x8 a0, a1, a2;
      if (ATYPE == 1) {
        a0 = *(const bf16x8*)&Asl[(ko * AQ + rt * 32 + l31) * 8];
      } else {
        a0 = *(const bf16x8*)&Asl[(ko * AQ + 0 * 64 + rt * 32 + l31) * 8];
        a1 = *(const bf16x8*)&Asl[(ko * AQ + 1 * 64 + rt * 32 + l31) * 8];
        a2 = *(const bf16x8*)&Asl[(ko * AQ + 2 * 64 + rt * 32 + l31) * 8];
      }
      bf16x8 b0[2], b1[2], b2[2];
#pragma unroll
      for (int ci = 0; ci < 2; ++ci) {
        const int cc = (cb + ci) * 32 + l31;
        b0[ci] = *(const bf16x8*)&Bl[(ko * BQ + 0 * 128 + cc) * 8];
        b1[ci] = *(const bf16x8*)&Bl[(ko * BQ + 1 * 128 + cc) * 8];
        b2[ci] = *(const bf16x8*)&Bl[(ko * BQ + 2 * 128 + cc) * 8];
      }
      if (ATYPE == 1) {
        acc0 = __builtin_amdgcn_mfma_f32_32x32x16_bf16(a0, b0[0], acc0, 0, 0, 0);
        acc1 = __builtin_amdgcn_mfma_f32_32x32x16_bf16(a0, b0[1], acc1, 0, 0, 0);
        acc0 = __builtin_amdgcn_mfma_f32_32x32x16_bf16(a0, b1[0], acc0, 0, 0, 0);
        acc1 = __builtin_amdgcn_mfma_f32_32x32x16_bf16(a0, b1[1], acc1, 0, 0, 0);
        acc0 = __builtin_amdgcn_mfma_f32_32x32x16_bf16(a0, b2[0], acc0, 0, 0, 0);
        acc1 = __builtin_amdgcn_mfma_f32_32x32x16_bf16(a0, b2[1], acc1, 0, 0, 0);
      } else {
        acc0 = __builtin_amdgcn_mfma_f32_32x32x16_bf16(a0, b0[0], acc0, 0, 0, 0);
        acc1 = __builtin_amdgcn_mfma_f32_32x32x16_bf16(a0, b0[1], acc1, 0, 0, 0);
        acc0 = __builtin_amdgcn_mfma_f32_32x32x16_bf16(a0, b1[0], acc0, 0, 0, 0);
        acc1 = __builtin_amdgcn_mfma_f32_32x32x16_bf16(a0, b1[1], acc1, 0, 0, 0);
        acc0 = __builtin_amdgcn_mfma_f32_32x32x16_bf16(a0, b2[0], acc0, 0, 0, 0);
        acc1 = __builtin_amdgcn_mfma_f32_32x32x16_bf16(a0, b2[1], acc1, 0, 0, 0);
        acc0 = __builtin_amdgcn_mfma_f32_32x32x16_bf16(a1, b0[0], acc0, 0, 0, 0);
        acc1 = __builtin_amdgcn_mfma_f32_32x32x16_bf16(a1, b0[1], acc1, 0, 0, 0);
        acc0 = __builtin_amdgcn_mfma_f32_32x32x16_bf16(a1, b1[0], acc0, 0, 0, 0);
        acc1 = __builtin_amdgcn_mfma_f32_32x32x16_bf16(a1, b1[1], acc1, 0, 0, 0);
        acc0 = __builtin_amdgcn_mfma_f32_32x32x16_bf16(a2, b0[0], acc0, 0, 0, 0);
        acc1 = __builtin_amdgcn_mfma_f32_32x32x16_bf16(a2, b0[1], acc1, 0, 0, 0);
      }
    }
    __syncthreads();
  }
  // ---- C scatter: 32x32 C/D map col=l31, row=(reg&3)+8*(reg>>2)+4*lh ----
  float* Cl = (float*)smem;
#pragma unroll
  for (int reg = 0; reg < 16; ++reg) {
    int row32 = (reg & 3) + 8 * (reg >> 2) + 4 * lh;
    int t = rt * 32 + row32;
    Cl[t * 132 + (cb + 0) * 32 + l31] = acc0[reg];
    Cl[t * 132 + (cb + 1) * 32 + l31] = acc1[reg];
  }
  __syncthreads();
  if (tid < 128) {
    const int c = tid;
    float v = 0.f;
    for (int t = 0; t < 64; ++t) {
      float pre = Cl[t * 132 + c];
      {
#pragma clang fp contract(off)
        float dlt = (pre - v) * 0.5f;  // v + (c-v)/tau, tau=2 (exact /2)
        v = v + dlt;
      }
      bool s = (v >= 1.0f);
      size_t orow = (size_t)(t * 4096 + bn);
      if (GATE) {
        float g = gate[orow * 128 + c];
        ((float*)outp)[orow * 128 + c] = s ? 0.f : g;  // g*(1-s) exact
      } else {
        ((unsigned short*)outp)[orow * NW + c0 + c] =
            s ? (unsigned short)0x3F80 : (unsigned short)0;  // bf16 1.0 / 0.0
      }
      v = s ? 0.f : v;  // hard reset
    }
  }
}

// ---------------------------------------------------------------------------
// Spiking 2-head attention per (t,b):  S = q k^T * 0.125 ; O = S v. No softmax.
// Exact in bf16 MFMA: spikes in {0,1}; S integer<=64 (bf16-exact after *1/8);
// O = multiples of 1/8 <= 512 (fp32-exact). Wave w owns n-rows [w*16,w*16+16).
// ---------------------------------------------------------------------------
__global__ __launch_bounds__(256) void k_attn(
    const unsigned short* __restrict__ q, const unsigned short* __restrict__ kk,
    const unsigned short* __restrict__ vv, float* __restrict__ o) {
  __shared__ unsigned short ql[64 * 136];  // [n][d] bf16 bits
  __shared__ unsigned short kl[64 * 136];
  __shared__ unsigned short vt[128 * 72];  // [d][m] (v transposed)
  __shared__ unsigned short sl[64 * 72];   // S' [n][m] per head (reused)
  const size_t base = (size_t)blockIdx.x * 8192;
#pragma unroll
  for (int i = 0; i < 4; ++i) {
    int idx8 = threadIdx.x + i * 256;     // 1024 x 8-elem chunks
    int n = idx8 >> 4, d8 = (idx8 & 15) * 8;
    uint4 pq = *(const uint4*)&q[base + n * 128 + d8];
    uint4 pk = *(const uint4*)&kk[base + n * 128 + d8];
    *(uint4*)&ql[n * 136 + d8] = pq;
    *(uint4*)&kl[n * 136 + d8] = pk;
    uint4 pv = *(const uint4*)&vv[base + n * 128 + d8];
    unsigned short e[8] = {
        (unsigned short)(pv.x & 0xFFFF), (unsigned short)(pv.x >> 16),
        (unsigned short)(pv.y & 0xFFFF), (unsigned short)(pv.y >> 16),
        (unsigned short)(pv.z & 0xFFFF), (unsigned short)(pv.z >> 16),
        (unsigned short)(pv.w & 0xFFFF), (unsigned short)(pv.w >> 16)};
#pragma unroll
    for (int j = 0; j < 8; ++j) vt[(d8 + j) * 72 + n] = e[j];
  }
  __syncthreads();
  const int lane = threadIdx.x & 63;
  const int w = threadIdx.x >> 6;          // wave id = n-tile (ti)
  const int l15 = lane & 15, l4 = lane >> 4;
  for (int h = 0; h < 2; ++h) {
    bf16x8 af0 = *(const bf16x8*)&ql[(w * 16 + l15) * 136 + h * 64 + l4 * 8];
    bf16x8 af1 = *(const bf16x8*)&ql[(w * 16 + l15) * 136 + h * 64 + 32 + l4 * 8];
#pragma unroll
    for (int tj = 0; tj < 4; ++tj) {
      f32x4 c = {0.f, 0.f, 0.f, 0.f};
      bf16x8 b0 = *(const bf16x8*)&kl[(tj * 16 + l15) * 136 + h * 64 + l4 * 8];
      c = __builtin_amdgcn_mfma_f32_16x16x32_bf16(af0, b0, c, 0, 0, 0);
      bf16x8 b1 = *(const bf16x8*)&kl[(tj * 16 + l15) * 136 + h * 64 + 32 + l4 * 8];
      c = __builtin_amdgcn_mfma_f32_16x16x32_bf16(af1, b1, c, 0, 0, 0);
#pragma unroll
      for (int r = 0; r < 4; ++r) {
        float sp = c[r] * 0.125f;  // exact; low 16 mantissa bits are zero
        sl[(w * 16 + l4 * 4 + r) * 72 + tj * 16 + l15] =
            (unsigned short)(__float_as_uint(sp) >> 16);
      }
    }
    __syncthreads();
    bf16x8 a20 = *(const bf16x8*)&sl[(w * 16 + l15) * 72 + l4 * 8];
    bf16x8 a21 = *(const bf16x8*)&sl[(w * 16 + l15) * 72 + 32 + l4 * 8];
#pragma unroll
    for (int tj = 0; tj < 4; ++tj) {
      f32x4 c = {0.f, 0.f, 0.f, 0.f};
      bf16x8 b0 = *(const bf16x8*)&vt[(h * 64 + tj * 16 + l15) * 72 + l4 * 8];
      c = __builtin_amdgcn_mfma_f32_16x16x32_bf16(a20, b0, c, 0, 0, 0);
      bf16x8 b1 = *(const bf16x8*)&vt[(h * 64 + tj * 16 + l15) * 72 + 32 + l4 * 8];
      c = __builtin_amdgcn_mfma_f32_16x16x32_bf16(a21, b1, c, 0, 0, 0);
#pragma unroll
      for (int r = 0; r < 4; ++r)
        o[base + (size_t)(w * 16 + l4 * 4 + r) * 128 + h * 64 + tj * 16 + l15] = c[r];
    }
    __syncthreads();  // sl reused by next head
  }
}

// ---------------------------------------------------------------------------
extern "C" void kernel_launch(void* const* d_in, const int* in_sizes, int n_in,
                              void* d_out, int out_size, void* d_ws, size_t ws_size,
                              hipStream_t stream) {
  const float* x  = (const float*)d_in[0];
  const float* mx = (const float*)d_in[1];
  const float* Wq = (const float*)d_in[2];
  const float* Wk = (const float*)d_in[3];
  const float* Wv = (const float*)d_in[4];
  const float* Wo = (const float*)d_in[5];
  const float* W1 = (const float*)d_in[6];
  const float* W2 = (const float*)d_in[7];
  float* out = (float*)d_out;

  // workspace layout (~449 MiB):
  char* w = (char*)d_ws;
  float* G = (float*)w;                                  // 16 KB
  unsigned short* wtq = (unsigned short*)(w + 16384);    // 3*128*128 halfs
  unsigned short* wtk = wtq + 3 * 16384;
  unsigned short* wtv = wtk + 3 * 16384;
  unsigned short* wto = wtv + 3 * 16384;
  unsigned short* wt1 = wto + 3 * 16384;                 // 3*128*256 halfs
  unsigned short* wt2 = wt1 + 3 * 32768;                 // 3*256*128 halfs
  float* xlp = (float*)(w + 1048576);                    // 134 MB, later o
  float* x2  = (float*)(w + 1048576 + 134217728ull);     // 134 MB
  unsigned short* sq = (unsigned short*)(w + 1048576 + 268435456ull);  // 67 MB
  unsigned short* sk = sq + 33554432ull;                 // 67 MB
  unsigned short* sv = sk + 33554432ull;                 // 67 MB
  unsigned short* sh = sq;  // mlp hidden spikes overlay sq+sk (134 MB)

  k_gram<<<64, 64, 0, stream>>>(G);
  k_prep<<<64, 256, 0, stream>>>(Wq, wtq, 128, 128);
  k_prep<<<64, 256, 0, stream>>>(Wk, wtk, 128, 128);
  k_prep<<<64, 256, 0, stream>>>(Wv, wtv, 128, 128);
  k_prep<<<64, 256, 0, stream>>>(Wo, wto, 128, 128);
  k_prep<<<128, 256, 0, stream>>>(W1, wt1, 128, 256);
  k_prep<<<128, 256, 0, stream>>>(W2, wt2, 256, 128);
  k_lowpass<<<4096, 256, 0, stream>>>(x, mx, G, xlp);
  // q from x; k,v from lowpassed memory stream
  k_mfma_lif<128, 0, false><<<dim3(4096, 1), 256, 0, stream>>>(x,   wtq, 128, nullptr, sq);
  k_mfma_lif<128, 0, false><<<dim3(4096, 1), 256, 0, stream>>>(xlp, wtk, 128, nullptr, sk);
  k_mfma_lif<128, 0, false><<<dim3(4096, 1), 256, 0, stream>>>(xlp, wtv, 128, nullptr, sv);
  k_attn<<<4096, 256, 0, stream>>>(sq, sk, sv, xlp);  // o overwrites xlp
  // attn_spk = lif(o @ Wo); x2 = x * (1 - attn_spk)
  k_mfma_lif<128, 0, true ><<<dim3(4096, 1), 256, 0, stream>>>(xlp, wto, 128, x, x2);
  // mlp: h = lif(x2 @ W1) (HID=256 -> grid.y=2); out = x2 * (1 - lif(h @ W2))
  k_mfma_lif<128, 0, false><<<dim3(4096, 2), 256, 0, stream>>>(x2, wt1, 256, nullptr, sh);
  k_mfma_lif<256, 1, true ><<<dim3(4096, 1), 256, 0, stream>>>(sh, wt2, 128, x2, out);
}